// Round 2
// baseline (7103.694 us; speedup 1.0000x reference)
//
#include <hip/hip_runtime.h>
#include <hip/hip_bf16.h>

#define BB 4
#define SS 4096
#define DD 512
#define LWW 512
#define CC 64
#define NCH 64
#define NBLK 128

typedef unsigned short u16;
using fragAB = __attribute__((ext_vector_type(8))) short;
using fragC  = __attribute__((ext_vector_type(4))) float;
using u16x4  = __attribute__((ext_vector_type(4))) short;

__device__ __forceinline__ short f2bf(float f){
  unsigned u = __float_as_uint(f);
  u = (u + 0x7FFFu + ((u >> 16) & 1u)) >> 16;
  return (short)u;
}
__device__ __forceinline__ float bf2f(short s){
  return __uint_as_float(((unsigned)(u16)s) << 16);
}
__device__ __forceinline__ fragC zeroC(){ fragC z = {0.f,0.f,0.f,0.f}; return z; }

__device__ __forceinline__ fragAB frag_bf16g(const u16* __restrict__ base, int ld, int r0, int k0, int lane){
  return *(const fragAB*)(base + (size_t)(r0 + (lane & 15)) * ld + k0 + ((lane >> 4) << 3));
}
__device__ __forceinline__ fragAB frag_lds(const short* base, int ld, int r0, int k0, int lane){
  return *(const fragAB*)(base + (r0 + (lane & 15)) * ld + k0 + ((lane >> 4) << 3));
}
#define MFMA16(a,b,c) __builtin_amdgcn_mfma_f32_16x16x32_bf16(a,b,c,0,0,0)

// ---------------- grid barrier (agent scope) ----------------
__device__ __forceinline__ void gridbar(unsigned* bar, unsigned target){
  __threadfence();
  __syncthreads();
  if (threadIdx.x == 0){
    __hip_atomic_fetch_add(bar, 1u, __ATOMIC_ACQ_REL, __HIP_MEMORY_SCOPE_AGENT);
    while (__hip_atomic_load(bar, __ATOMIC_ACQUIRE, __HIP_MEMORY_SCOPE_AGENT) < target)
      __builtin_amdgcn_s_sleep(2);
  }
  __syncthreads();
}

// ---------------- init state ----------------
__global__ void k_init(const float* __restrict__ iw1, const float* __restrict__ ib1,
                       const float* __restrict__ iw2, const float* __restrict__ ib2,
                       float* __restrict__ w1, float* __restrict__ mw1,
                       float* __restrict__ w2b, float* __restrict__ mw2,
                       float* __restrict__ b1, float* __restrict__ mb1,
                       float* __restrict__ b2, float* __restrict__ mb2,
                       unsigned* __restrict__ bar){
  int i = blockIdx.x * 256 + threadIdx.x;
  if (i == 0) *bar = 0u;
  if (i < LWW * DD){
    float a = iw1[i], c = iw2[i];
#pragma unroll
    for (int b = 0; b < BB; ++b){
      w1 [(size_t)b*LWW*DD + i] = a;  mw1[(size_t)b*LWW*DD + i] = 0.f;
      w2b[(size_t)b*DD*LWW + i] = c;  mw2[(size_t)b*DD*LWW + i] = 0.f;
    }
  }
  if (i < LWW){
    float v1 = ib1[i], v2 = ib2[i];
#pragma unroll
    for (int b = 0; b < BB; ++b){
      b1[b*LWW+i] = v1; mb1[b*LWW+i] = 0.f;
      b2[b*DD +i] = v2; mb2[b*DD +i] = 0.f;
    }
  }
}

// ---------------- fp32 -> bf16 conversions (x, W concat) ----------------
__global__ __launch_bounds__(256) void k_cvt(const float* __restrict__ x,
    const float* __restrict__ Wq, const float* __restrict__ Wk, const float* __restrict__ Wv,
    u16* __restrict__ xb, u16* __restrict__ Wc){
  size_t i = (size_t)blockIdx.x * 256 + threadIdx.x;
  const size_t NX4 = (size_t)BB*SS*DD/4;   // 2097152
  const size_t NW4 = (size_t)DD*DD/4;      // 65536 per W
  if (i < NX4){
    float4 v = ((const float4*)x)[i];
    u16x4 o = { f2bf(v.x), f2bf(v.y), f2bf(v.z), f2bf(v.w) };
    *(u16x4*)(xb + 4*i) = o;
  } else if (i < NX4 + 3*NW4){
    size_t j = i - NX4;
    const float* src = (j < NW4) ? Wq : (j < 2*NW4) ? Wk : Wv;
    size_t jj = j % NW4;
    float4 v = ((const float4*)src)[jj];
    u16x4 o = { f2bf(v.x), f2bf(v.y), f2bf(v.z), f2bf(v.w) };
    *(u16x4*)(Wc + 4*j) = o;
  }
}

// ---------------- Q,K,V projections (bf16 inputs) ----------------
__global__ __launch_bounds__(256) void k_proj(const u16* __restrict__ xb,
    const u16* __restrict__ Wc,
    u16* __restrict__ Qb, u16* __restrict__ Kb, float* __restrict__ V){
  int mt = blockIdx.x / 12, nt = blockIdx.x % 12;
  int lane = threadIdx.x & 63, wid = threadIdx.x >> 6;
  int m0 = mt * 64 + wid * 16;
  const u16* Bp = Wc + (size_t)nt * 128 * DD;
  fragC acc[8];
#pragma unroll
  for (int i = 0; i < 8; ++i) acc[i] = zeroC();
  for (int k0 = 0; k0 < DD; k0 += 32){
    fragAB a = frag_bf16g(xb, DD, m0, k0, lane);
#pragma unroll
    for (int nf = 0; nf < 8; ++nf)
      acc[nf] = MFMA16(a, frag_bf16g(Bp, DD, nf*16, k0, lane), acc[nf]);
  }
#pragma unroll
  for (int nf = 0; nf < 8; ++nf){
#pragma unroll
    for (int r = 0; r < 4; ++r){
      int m = m0 + ((lane >> 4) << 2) + r;
      int col = nt*128 + nf*16 + (lane & 15);
      float v = acc[nf][r];
      if (nt < 4)      Qb[(size_t)m*DD + col]        = (u16)f2bf(v);
      else if (nt < 8) Kb[(size_t)m*DD + col - 512]  = (u16)f2bf(v);
      else             V [(size_t)m*DD + col - 1024] = v;
    }
  }
}

// ---------------- l2-normalize Q,K rows in place ----------------
__global__ __launch_bounds__(256) void k_norm(u16* __restrict__ Qb, u16* __restrict__ Kb){
  int idx = blockIdx.x * 4 + (threadIdx.x >> 6);
  int lane = threadIdx.x & 63;
  u16* p = (idx < BB*SS ? Qb + (size_t)idx * DD
                        : Kb + (size_t)(idx - BB*SS) * DD) + lane * 8;
  fragAB v = *(const fragAB*)p;
  float f[8]; float s = 0.f;
#pragma unroll
  for (int i = 0; i < 8; ++i){ f[i] = bf2f(v[i]); s += f[i]*f[i]; }
#pragma unroll
  for (int o = 32; o > 0; o >>= 1) s += __shfl_xor(s, o, 64);
  float inv = 1.f / fmaxf(sqrtf(s), 1e-12f);
  fragAB o8;
#pragma unroll
  for (int i = 0; i < 8; ++i) o8[i] = f2bf(f[i] * inv);
  *(fragAB*)p = o8;
}

// ---------------- transpose K: Kb[b*S][D] -> KT[b][D][S] ----------------
__global__ __launch_bounds__(256) void k_trans(const u16* __restrict__ Kb, u16* __restrict__ KT){
  __shared__ short tile[64][68];
  int blk = blockIdx.x;
  int b = blk >> 9, rem = blk & 511;
  int st = rem >> 3, dt = rem & 7;
  int s0 = st*64, d0 = dt*64;
  int sr = threadIdx.x & 63, q = threadIdx.x >> 6;
  const u16* src = Kb + ((size_t)b*SS + s0 + sr)*DD + d0 + q*16;
  fragAB v0 = *(const fragAB*)src;
  fragAB v1 = *(const fragAB*)(src + 8);
#pragma unroll
  for (int i = 0; i < 8; ++i){ tile[sr][q*16+i] = v0[i]; tile[sr][q*16+8+i] = v1[i]; }
  __syncthreads();
  fragAB o0, o1;
#pragma unroll
  for (int i = 0; i < 8; ++i){ o0[i] = tile[q*16+i][sr]; o1[i] = tile[q*16+8+i][sr]; }
  u16* dst = KT + ((size_t)b*DD + d0 + sr)*SS + s0 + q*16;
  *(fragAB*)dst = o0;
  *(fragAB*)(dst + 8) = o1;
}

// ---------------- gates a,e,theta per (batch, chunk) ----------------
__global__ __launch_bounds__(256) void k_gates(const float* __restrict__ x,
    const float* __restrict__ aw, const float* __restrict__ ab,
    const float* __restrict__ ew, const float* __restrict__ eb,
    const float* __restrict__ tw, const float* __restrict__ tb,
    float* __restrict__ aet){
  __shared__ float part[64][4][3];
  __shared__ float rowsig[64][3];
  int b = blockIdx.x >> 6, t = blockIdx.x & 63;
  int tid = threadIdx.x;
  int r = tid >> 2, p = tid & 3;
  const float4* xp = (const float4*)(x + ((size_t)b*SS + (size_t)t*CC + r) * DD + p * 128);
  const float4* a4 = (const float4*)(aw + p*128);
  const float4* e4 = (const float4*)(ew + p*128);
  const float4* t4 = (const float4*)(tw + p*128);
  float s0 = 0.f, s1 = 0.f, s2 = 0.f;
  for (int i = 0; i < 32; ++i){
    float4 xv = xp[i], av = a4[i], ev = e4[i], tv = t4[i];
    s0 += xv.x*av.x + xv.y*av.y + xv.z*av.z + xv.w*av.w;
    s1 += xv.x*ev.x + xv.y*ev.y + xv.z*ev.z + xv.w*ev.w;
    s2 += xv.x*tv.x + xv.y*tv.y + xv.z*tv.z + xv.w*tv.w;
  }
  part[r][p][0] = s0; part[r][p][1] = s1; part[r][p][2] = s2;
  __syncthreads();
  if (tid < 64){
    float a_ = part[tid][0][0]+part[tid][1][0]+part[tid][2][0]+part[tid][3][0] + ab[0];
    float e_ = part[tid][0][1]+part[tid][1][1]+part[tid][2][1]+part[tid][3][1] + eb[0];
    float t_ = part[tid][0][2]+part[tid][1][2]+part[tid][2][2]+part[tid][3][2] + tb[0];
    rowsig[tid][0] = 1.f/(1.f+expf(-a_));
    rowsig[tid][1] = 1.f/(1.f+expf(-e_));
    rowsig[tid][2] = 1.f/(1.f+expf(-t_));
  }
  __syncthreads();
  if (tid < 3){
    float s = 0.f;
    for (int i = 0; i < 64; ++i) s += rowsig[i][tid];
    aet[((size_t)b*NCH + t)*3 + tid] = s * (1.f/64.f);
  }
}

// ---------------- persistent fused scan ----------------
__global__ __launch_bounds__(256, 1) void k_scan(
    const u16* __restrict__ Qb, const u16* __restrict__ Kb, const u16* __restrict__ KTg,
    const float* __restrict__ V, const float* __restrict__ aet,
    float* __restrict__ w1, float* __restrict__ mw1,
    float* __restrict__ b1, float* __restrict__ mb1,
    float* __restrict__ w2b, float* __restrict__ mw2,
    float* __restrict__ b2, float* __restrict__ mb2,
    u16* __restrict__ hkb, u16* __restrict__ hqs, u16* __restrict__ hkT,
    u16* __restrict__ dvpb, float* __restrict__ actd,
    float* __restrict__ out, unsigned* __restrict__ bar)
{
  __shared__ __align__(16) short s_w1[16*520];   // phase A: w2T/w1 tile ; phase B: w2old d-tile
  __shared__ __align__(16) short s_small[16*72]; // dhT / dvT
  __shared__ float s_bias[16];

  const int tid  = threadIdx.x;
  const int lane = tid & 63;
  const int wid  = tid >> 6;
  const int b    = blockIdx.x >> 5;
  const int tl   = blockIdx.x & 31;
  const int h0   = tl * 16;              // phase A tile
  const int d0   = tl * 16;              // phase B tile
  const size_t W1OFF = (size_t)b * LWW * DD;
  const size_t W2OFF = (size_t)b * DD * LWW;
  const size_t WBUFE = (size_t)BB * DD * LWW;
  unsigned barp = 0;

  for (int t = 0; t < NCH; ++t){
    // ======== PHASE A ========
    if (t > 0){
      const float* w2A = w2b + (size_t)((t+1)&1)*WBUFE + W2OFF;
      { // stage w2T tile: s_w1[h][d] = w2A[d][h0+h]
        int h = tid & 15, db = tid >> 4;
        for (int j = 0; j < 32; ++j){
          int d = db + j*16;
          s_w1[h*520 + d] = f2bf(w2A[(size_t)d*LWW + h0 + h]);
        }
      }
      __syncthreads();
      { // dh[c][hl] = (dvp @ w2T) * actder  -> s_small
        int m0 = wid * 16;
        fragC a0 = zeroC();
        const u16* dv = dvpb + (size_t)b*CC*DD;
        for (int k0 = 0; k0 < DD; k0 += 32)
          a0 = MFMA16(frag_bf16g(dv, DD, m0, k0, lane), frag_lds(s_w1, 520, 0, k0, lane), a0);
        const float* ad = actd + (size_t)b*CC*LWW;
        int hl = lane & 15;
#pragma unroll
        for (int r = 0; r < 4; ++r){
          int c = m0 + ((lane >> 4) << 2) + r;
          s_small[hl*72 + c] = f2bf(a0[r] * ad[(size_t)c*LWW + h0 + hl]);
        }
      }
      __syncthreads();
      { // g_w1 [16h][512d], K=64 over c; then w1/mw1/b1 updates
        int n0w = wid * 128;
        fragC accg[8];
#pragma unroll
        for (int i = 0; i < 8; ++i) accg[i] = zeroC();
        const u16* KT = KTg + (size_t)b*DD*SS + (size_t)(t-1)*CC;
#pragma unroll
        for (int kk = 0; kk < 2; ++kk){
          int k0 = kk * 32;
          fragAB af = frag_lds(s_small, 72, 0, k0, lane);
#pragma unroll
          for (int nf = 0; nf < 8; ++nf)
            accg[nf] = MFMA16(af, frag_bf16g(KT, SS, n0w + nf*16, k0, lane), accg[nf]);
        }
        const float* g3 = aet + ((size_t)b*NCH + (t-1)) * 3;
        float ga = g3[0], ge = g3[1], gth = g3[2];
#pragma unroll
        for (int nf = 0; nf < 8; ++nf)
#pragma unroll
          for (int r = 0; r < 4; ++r){
            int h = h0 + ((lane >> 4) << 2) + r;
            int d = n0w + nf*16 + (lane & 15);
            size_t idx = W1OFF + (size_t)h*DD + d;
            float g  = accg[nf][r] * (1.f/64.f);
            float m_ = ge*mw1[idx] - gth*g;
            float w_ = (1.f-ga)*w1[idx] + m_;
            mw1[idx] = m_; w1[idx] = w_;
            s_w1[(h-h0)*520 + d] = f2bf(w_);
          }
        if (tid < 16){
          int h = h0 + tid;
          float s = 0.f;
          for (int c = 0; c < CC; ++c) s += bf2f(s_small[tid*72 + c]);
          float gb = s * (1.f/64.f);
          float m_ = ge*mb1[b*LWW+h] - gth*gb;
          float bn = (1.f-ga)*b1[b*LWW+h] + m_;
          mb1[b*LWW+h] = m_; b1[b*LWW+h] = bn;
          s_bias[tid] = bn;
        }
      }
    } else {
      // t == 0: load initial w1 tile + b1
      int h = tid & 15, db = tid >> 4;
      for (int j = 0; j < 32; ++j){
        int d = db + j*16;
        s_w1[h*520 + d] = f2bf(w1[W1OFF + (size_t)(h0+h)*DD + d]);
      }
      if (tid < 16) s_bias[tid] = b1[b*LWW + h0 + tid];
    }
    __syncthreads();
    { // pre & hq for chunk t
      const u16* Kc = Kb + ((size_t)b*SS + (size_t)t*CC) * DD;
      const u16* Qc = Qb + ((size_t)b*SS + (size_t)t*CC) * DD;
      int m0 = wid * 16;
      fragC ak_ = zeroC(), aq_ = zeroC();
      for (int k0 = 0; k0 < DD; k0 += 32){
        fragAB bf = frag_lds(s_w1, 520, 0, k0, lane);
        ak_ = MFMA16(frag_bf16g(Kc, DD, m0, k0, lane), bf, ak_);
        aq_ = MFMA16(frag_bf16g(Qc, DD, m0, k0, lane), bf, aq_);
      }
      int hl = lane & 15;
      float bb = s_bias[hl];
      u16x4 pk;
#pragma unroll
      for (int r = 0; r < 4; ++r){
        int c = m0 + ((lane >> 4) << 2) + r;
        float pre = ak_[r] + bb;
        float sg  = 1.f/(1.f+expf(-pre));
        float hkv = pre * sg;
        float adv = sg * (1.f + pre * (1.f - sg));
        size_t oi = ((size_t)b*CC + c)*LWW + h0 + hl;
        short hb = f2bf(hkv);
        hkb[oi]  = (u16)hb;
        actd[oi] = adv;
        float hqv = aq_[r] + bb;
        float s2  = 1.f/(1.f+expf(-hqv));
        hqs[oi] = (u16)f2bf(hqv * s2);
        pk[r] = hb;
      }
      int c0 = m0 + ((lane >> 4) << 2);
      *(u16x4*)(hkT + ((size_t)b*LWW + h0 + hl)*CC + c0) = pk;
    }
    barp += NBLK; gridbar(bar, barp);

    // ======== PHASE B ========
    const float* w2o = w2b + (size_t)(t&1)*WBUFE + W2OFF;
    float*       w2n = w2b + (size_t)((t+1)&1)*WBUFE + W2OFF;
    { // stage w2o d-tile: s_w1[dd][h]
      for (int j = 0; j < 32; ++j){
        int e = j*256 + tid;
        int dd = e >> 9, h = e & 511;
        s_w1[dd*520 + h] = f2bf(w2o[(size_t)(d0+dd)*LWW + h]);
      }
      if (tid < 16) s_bias[tid] = b2[b*DD + d0 + tid];
    }
    __syncthreads();
    { // y, vp, dvp
      const u16* hqp = hqs + (size_t)b*CC*LWW;
      const u16* hkp = hkb + (size_t)b*CC*LWW;
      int m0 = wid * 16;
      fragC ya = zeroC(), va = zeroC();
      for (int k0 = 0; k0 < LWW; k0 += 32){
        fragAB bf = frag_lds(s_w1, 520, 0, k0, lane);
        ya = MFMA16(frag_bf16g(hqp, LWW, m0, k0, lane), bf, ya);
        va = MFMA16(frag_bf16g(hkp, LWW, m0, k0, lane), bf, va);
      }
      int dd = lane & 15;
      int d  = d0 + dd;
      float bb = s_bias[dd];
#pragma unroll
      for (int r = 0; r < 4; ++r){
        int c = m0 + ((lane >> 4) << 2) + r;
        size_t oi = ((size_t)b*SS + (size_t)t*CC + c) * DD + d;
        out[oi] = ya[r] + bb;
        float dvv = (va[r] + bb - V[oi]) * (2.f/512.f);
        short db_ = f2bf(dvv);
        dvpb[((size_t)b*CC + c)*DD + d] = (u16)db_;
        s_small[dd*72 + c] = db_;
      }
    }
    __syncthreads();
    { // g_w2 [16d][512h], K=64 over c; then w2/mw2/b2 updates
      int n0w = wid * 128;
      fragC accg[8];
#pragma unroll
      for (int i = 0; i < 8; ++i) accg[i] = zeroC();
      const u16* hT = hkT + (size_t)b*LWW*CC;
#pragma unroll
      for (int kk = 0; kk < 2; ++kk){
        int k0 = kk * 32;
        fragAB af = frag_lds(s_small, 72, 0, k0, lane);
#pragma unroll
        for (int nf = 0; nf < 8; ++nf)
          accg[nf] = MFMA16(af, frag_bf16g(hT, CC, n0w + nf*16, k0, lane), accg[nf]);
      }
      const float* g3 = aet + ((size_t)b*NCH + t) * 3;
      float ga = g3[0], ge = g3[1], gth = g3[2];
#pragma unroll
      for (int nf = 0; nf < 8; ++nf)
#pragma unroll
        for (int r = 0; r < 4; ++r){
          int d = d0 + ((lane >> 4) << 2) + r;
          int h = n0w + nf*16 + (lane & 15);
          size_t idx = (size_t)d*LWW + h;
          float g  = accg[nf][r] * (1.f/64.f);
          float m_ = ge*mw2[W2OFF + idx] - gth*g;
          float w_ = (1.f-ga)*w2o[idx] + m_;
          mw2[W2OFF + idx] = m_; w2n[idx] = w_;
        }
      if (tid < 16){
        int d = d0 + tid;
        float s = 0.f;
        for (int c2 = 0; c2 < CC; ++c2) s += bf2f(s_small[tid*72 + c2]);
        float gb = s * (1.f/64.f);
        float m_ = ge*mb2[b*DD+d] - gth*gb;
        float bn = (1.f-ga)*b2[b*DD+d] + m_;
        mb2[b*DD+d] = m_; b2[b*DD+d] = bn;
      }
    }
    barp += NBLK; gridbar(bar, barp);
  }
}

extern "C" void kernel_launch(void* const* d_in, const int* in_sizes, int n_in,
                              void* d_out, int out_size, void* d_ws, size_t ws_size,
                              hipStream_t stream){
  const float* x   = (const float*)d_in[0];
  const float* Wq  = (const float*)d_in[1];
  const float* Wk  = (const float*)d_in[2];
  const float* Wv  = (const float*)d_in[3];
  const float* iw1 = (const float*)d_in[4];
  const float* ib1 = (const float*)d_in[5];
  const float* iw2 = (const float*)d_in[6];
  const float* ib2 = (const float*)d_in[7];
  const float* aw  = (const float*)d_in[8];
  const float* ab  = (const float*)d_in[9];
  const float* ew  = (const float*)d_in[10];
  const float* eb  = (const float*)d_in[11];
  const float* tw  = (const float*)d_in[12];
  const float* tb  = (const float*)d_in[13];
  float* out = (float*)d_out;

  float* fw = (float*)d_ws;
  float* V    = fw;  fw += (size_t)BB*SS*DD;
  float* w1   = fw;  fw += (size_t)BB*LWW*DD;
  float* mw1  = fw;  fw += (size_t)BB*LWW*DD;
  float* w2b  = fw;  fw += (size_t)2*BB*DD*LWW;
  float* mw2  = fw;  fw += (size_t)BB*DD*LWW;
  float* b1   = fw;  fw += BB*LWW;
  float* mb1  = fw;  fw += BB*LWW;
  float* b2   = fw;  fw += BB*DD;
  float* mb2  = fw;  fw += BB*DD;
  float* actd = fw;  fw += (size_t)BB*CC*LWW;
  float* aet  = fw;  fw += (size_t)BB*NCH*3;
  unsigned* bar = (unsigned*)fw; fw += 64;
  u16* xb   = (u16*)fw;                      // also aliased as KTg (xb dead after k_proj)
  u16* Wc   = xb  + (size_t)BB*SS*DD;
  u16* Qb   = Wc  + (size_t)3*DD*DD;
  u16* Kb   = Qb  + (size_t)BB*SS*DD;
  u16* hkb  = Kb  + (size_t)BB*SS*DD;
  u16* hqs  = hkb + (size_t)BB*CC*LWW;
  u16* hkT  = hqs + (size_t)BB*CC*LWW;
  u16* dvpb = hkT + (size_t)BB*CC*LWW;
  u16* KTg  = xb;  // alias: liveness of xb ends at k_proj; KTg written by k_trans after

  k_init <<<1024, 256, 0, stream>>>(iw1, ib1, iw2, ib2, w1, mw1, w2b, mw2, b1, mb1, b2, mb2, bar);
  k_cvt  <<<8960, 256, 0, stream>>>(x, Wq, Wk, Wv, xb, Wc);
  k_proj <<<3072, 256, 0, stream>>>(xb, Wc, Qb, Kb, V);
  k_norm <<<8192, 256, 0, stream>>>(Qb, Kb);
  k_trans<<<2048, 256, 0, stream>>>(Kb, KTg);
  k_gates<<<256,  256, 0, stream>>>(x, aw, ab, ew, eb, tw, tb, aet);
  k_scan <<<NBLK, 256, 0, stream>>>(Qb, Kb, KTg, V, aet, w1, mw1, b1, mb1,
                                    w2b, mw2, b2, mb2, hkb, hqs, hkT, dvpb, actd, out, bar);
}

// Round 3
// 5785.358 us; speedup vs baseline: 1.2279x; 1.2279x over previous
//
#include <hip/hip_runtime.h>
#include <hip/hip_bf16.h>

#define BB 4
#define SS 4096
#define DD 512
#define LWW 512
#define CC 64
#define NCH 64

typedef unsigned short u16;
using fragAB = __attribute__((ext_vector_type(8))) short;
using fragC  = __attribute__((ext_vector_type(4))) float;
using u16x4  = __attribute__((ext_vector_type(4))) short;

__device__ __forceinline__ short f2bf(float f){
  unsigned u = __float_as_uint(f);
  u = (u + 0x7FFFu + ((u >> 16) & 1u)) >> 16;
  return (short)u;
}
__device__ __forceinline__ float bf2f(short s){
  return __uint_as_float(((unsigned)(u16)s) << 16);
}
__device__ __forceinline__ fragC zeroC(){ fragC z = {0.f,0.f,0.f,0.f}; return z; }

__device__ __forceinline__ fragAB frag_bf16g(const u16* __restrict__ base, int ld, int r0, int k0, int lane){
  return *(const fragAB*)(base + (size_t)(r0 + (lane & 15)) * ld + k0 + ((lane >> 4) << 3));
}
__device__ __forceinline__ fragAB frag_lds(const short* base, int ld, int r0, int k0, int lane){
  return *(const fragAB*)(base + (r0 + (lane & 15)) * ld + k0 + ((lane >> 4) << 3));
}
#define MFMA16(a,b,c) __builtin_amdgcn_mfma_f32_16x16x32_bf16(a,b,c,0,0,0)

// ---------------- per-batch barrier (agent scope) ----------------
__device__ __forceinline__ void batchbar(unsigned* bar, unsigned target){
  __threadfence();
  __syncthreads();
  if (threadIdx.x == 0){
    __hip_atomic_fetch_add(bar, 1u, __ATOMIC_ACQ_REL, __HIP_MEMORY_SCOPE_AGENT);
    while (__hip_atomic_load(bar, __ATOMIC_ACQUIRE, __HIP_MEMORY_SCOPE_AGENT) < target)
      __builtin_amdgcn_s_sleep(1);
  }
  __syncthreads();
}

// ---------------- fp32 -> bf16 conversions (x, W concat) + bar zero ----------------
__global__ __launch_bounds__(256) void k_cvt(const float* __restrict__ x,
    const float* __restrict__ Wq, const float* __restrict__ Wk, const float* __restrict__ Wv,
    u16* __restrict__ xb, u16* __restrict__ Wc, unsigned* __restrict__ bar){
  size_t i = (size_t)blockIdx.x * 256 + threadIdx.x;
  if (blockIdx.x == 0 && threadIdx.x < 128) bar[threadIdx.x] = 0u;
  const size_t NX4 = (size_t)BB*SS*DD/4;
  const size_t NW4 = (size_t)DD*DD/4;
  if (i < NX4){
    float4 v = ((const float4*)x)[i];
    u16x4 o = { f2bf(v.x), f2bf(v.y), f2bf(v.z), f2bf(v.w) };
    *(u16x4*)(xb + 4*i) = o;
  } else if (i < NX4 + 3*NW4){
    size_t j = i - NX4;
    const float* src = (j < NW4) ? Wq : (j < 2*NW4) ? Wk : Wv;
    size_t jj = j % NW4;
    float4 v = ((const float4*)src)[jj];
    u16x4 o = { f2bf(v.x), f2bf(v.y), f2bf(v.z), f2bf(v.w) };
    *(u16x4*)(Wc + 4*j) = o;
  }
}

// ---------------- Q,K,V projections (bf16 inputs) ----------------
__global__ __launch_bounds__(256) void k_proj(const u16* __restrict__ xb,
    const u16* __restrict__ Wc,
    u16* __restrict__ Qb, u16* __restrict__ Kb, float* __restrict__ V){
  int mt = blockIdx.x / 12, nt = blockIdx.x % 12;
  int lane = threadIdx.x & 63, wid = threadIdx.x >> 6;
  int m0 = mt * 64 + wid * 16;
  const u16* Bp = Wc + (size_t)nt * 128 * DD;
  fragC acc[8];
#pragma unroll
  for (int i = 0; i < 8; ++i) acc[i] = zeroC();
  for (int k0 = 0; k0 < DD; k0 += 32){
    fragAB a = frag_bf16g(xb, DD, m0, k0, lane);
#pragma unroll
    for (int nf = 0; nf < 8; ++nf)
      acc[nf] = MFMA16(a, frag_bf16g(Bp, DD, nf*16, k0, lane), acc[nf]);
  }
#pragma unroll
  for (int nf = 0; nf < 8; ++nf){
#pragma unroll
    for (int r = 0; r < 4; ++r){
      int m = m0 + ((lane >> 4) << 2) + r;
      int col = nt*128 + nf*16 + (lane & 15);
      float v = acc[nf][r];
      if (nt < 4)      Qb[(size_t)m*DD + col]        = (u16)f2bf(v);
      else if (nt < 8) Kb[(size_t)m*DD + col - 512]  = (u16)f2bf(v);
      else             V [(size_t)m*DD + col - 1024] = v;
    }
  }
}

// ---------------- l2-normalize Q,K rows in place ----------------
__global__ __launch_bounds__(256) void k_norm(u16* __restrict__ Qb, u16* __restrict__ Kb){
  int idx = blockIdx.x * 4 + (threadIdx.x >> 6);
  int lane = threadIdx.x & 63;
  u16* p = (idx < BB*SS ? Qb + (size_t)idx * DD
                        : Kb + (size_t)(idx - BB*SS) * DD) + lane * 8;
  fragAB v = *(const fragAB*)p;
  float f[8]; float s = 0.f;
#pragma unroll
  for (int i = 0; i < 8; ++i){ f[i] = bf2f(v[i]); s += f[i]*f[i]; }
#pragma unroll
  for (int o = 32; o > 0; o >>= 1) s += __shfl_xor(s, o, 64);
  float inv = 1.f / fmaxf(sqrtf(s), 1e-12f);
  fragAB o8;
#pragma unroll
  for (int i = 0; i < 8; ++i) o8[i] = f2bf(f[i] * inv);
  *(fragAB*)p = o8;
}

// ---------------- transpose K: Kb[b*S][D] -> KT[b][D][S] ----------------
__global__ __launch_bounds__(256) void k_trans(const u16* __restrict__ Kb, u16* __restrict__ KT){
  __shared__ short tile[64][68];
  int blk = blockIdx.x;
  int b = blk >> 9, rem = blk & 511;
  int st = rem >> 3, dt = rem & 7;
  int s0 = st*64, d0 = dt*64;
  int sr = threadIdx.x & 63, q = threadIdx.x >> 6;
  const u16* src = Kb + ((size_t)b*SS + s0 + sr)*DD + d0 + q*16;
  fragAB v0 = *(const fragAB*)src;
  fragAB v1 = *(const fragAB*)(src + 8);
#pragma unroll
  for (int i = 0; i < 8; ++i){ tile[sr][q*16+i] = v0[i]; tile[sr][q*16+8+i] = v1[i]; }
  __syncthreads();
  fragAB o0, o1;
#pragma unroll
  for (int i = 0; i < 8; ++i){ o0[i] = tile[q*16+i][sr]; o1[i] = tile[q*16+8+i][sr]; }
  u16* dst = KT + ((size_t)b*DD + d0 + sr)*SS + s0 + q*16;
  *(fragAB*)dst = o0;
  *(fragAB*)(dst + 8) = o1;
}

// ---------------- gates a,e,theta per (batch, chunk) ----------------
__global__ __launch_bounds__(256) void k_gates(const float* __restrict__ x,
    const float* __restrict__ aw, const float* __restrict__ ab,
    const float* __restrict__ ew, const float* __restrict__ eb,
    const float* __restrict__ tw, const float* __restrict__ tb,
    float* __restrict__ aet){
  __shared__ float part[64][4][3];
  __shared__ float rowsig[64][3];
  int b = blockIdx.x >> 6, t = blockIdx.x & 63;
  int tid = threadIdx.x;
  int r = tid >> 2, p = tid & 3;
  const float4* xp = (const float4*)(x + ((size_t)b*SS + (size_t)t*CC + r) * DD + p * 128);
  const float4* a4 = (const float4*)(aw + p*128);
  const float4* e4 = (const float4*)(ew + p*128);
  const float4* t4 = (const float4*)(tw + p*128);
  float s0 = 0.f, s1 = 0.f, s2 = 0.f;
  for (int i = 0; i < 32; ++i){
    float4 xv = xp[i], av = a4[i], ev = e4[i], tv = t4[i];
    s0 += xv.x*av.x + xv.y*av.y + xv.z*av.z + xv.w*av.w;
    s1 += xv.x*ev.x + xv.y*ev.y + xv.z*ev.z + xv.w*ev.w;
    s2 += xv.x*tv.x + xv.y*tv.y + xv.z*tv.z + xv.w*tv.w;
  }
  part[r][p][0] = s0; part[r][p][1] = s1; part[r][p][2] = s2;
  __syncthreads();
  if (tid < 64){
    float a_ = part[tid][0][0]+part[tid][1][0]+part[tid][2][0]+part[tid][3][0] + ab[0];
    float e_ = part[tid][0][1]+part[tid][1][1]+part[tid][2][1]+part[tid][3][1] + eb[0];
    float t_ = part[tid][0][2]+part[tid][1][2]+part[tid][2][2]+part[tid][3][2] + tb[0];
    rowsig[tid][0] = 1.f/(1.f+expf(-a_));
    rowsig[tid][1] = 1.f/(1.f+expf(-e_));
    rowsig[tid][2] = 1.f/(1.f+expf(-t_));
  }
  __syncthreads();
  if (tid < 3){
    float s = 0.f;
    for (int i = 0; i < 64; ++i) s += rowsig[i][tid];
    aet[((size_t)b*NCH + t)*3 + tid] = s * (1.f/64.f);
  }
}

// ---------------- persistent fused scan: state in registers ----------------
// grid: 128 blocks x 512 threads. block <-> (b, tl): blockIdx = 2b + (tl&1) + 8*(tl>>1)
// block owns w1[h0:h0+16][:], mw1; w2[d0:d0+16][:], mw2 (h0 = d0 = tl*16), fp32 in regs.
__global__ __launch_bounds__(512, 2) void k_scan(
    const u16* __restrict__ Qb, const u16* __restrict__ Kb, const u16* __restrict__ KTg,
    const float* __restrict__ V, const float* __restrict__ aet,
    const float* __restrict__ iw1, const float* __restrict__ ib1,
    const float* __restrict__ iw2, const float* __restrict__ ib2,
    u16* __restrict__ hkb, u16* __restrict__ hqs, u16* __restrict__ hkT,
    u16* __restrict__ dvpb, u16* __restrict__ w2Tb,
    float* __restrict__ out, unsigned* __restrict__ barb)
{
  __shared__ __align__(16) short s_w1[16*520];
  __shared__ __align__(16) short s_w2[16*520];
  __shared__ __align__(16) short s_t[16*72];
  __shared__ float s_b1[16], s_mb1[16], s_b2[16], s_mb2[16];

  const int tid  = threadIdx.x;
  const int lane = tid & 63;
  const int wid  = tid >> 6;
  const int q    = lane >> 4;
  const int l15  = lane & 15;
  const int b    = (blockIdx.x & 7) >> 1;
  const int tl   = ((blockIdx.x >> 3) << 1) | (blockIdx.x & 1);
  const int h0   = tl * 16;
  const int d0   = tl * 16;
  unsigned* bar  = barb + b * 32;
  unsigned  tgt  = 0;

  const u16* Kball = Kb  + (size_t)b*SS*DD;
  const u16* Qball = Qb  + (size_t)b*SS*DD;
  const u16* KTbat = KTg + (size_t)b*DD*SS;
  u16* hk_b  = hkb  + (size_t)b*CC*LWW;
  u16* hq_b  = hqs  + (size_t)b*CC*LWW;
  u16* hkT_b = hkT  + (size_t)b*LWW*CC;
  u16* dv_b  = dvpb + (size_t)b*CC*DD;
  const size_t W2TBUF = (size_t)BB*DD*LWW;

  // persistent register state
  float w1f[16], mw1f[16], w2f[16], mw2f[16], actr[4];

  // ---- preamble: init state from iw1/ib1/iw2/ib2 ----
  {
    u16* w2T1 = w2Tb + W2TBUF + (size_t)b*DD*LWW;   // buf[1] = initial w2T
#pragma unroll
    for (int nf = 0; nf < 4; ++nf){
      u16x4 pk;
#pragma unroll
      for (int r = 0; r < 4; ++r){
        int hr = q*4 + r;
        int dcol = wid*64 + nf*16 + l15;
        float a = iw1[(size_t)(h0 + hr)*DD + dcol];
        w1f[nf*4+r] = a; mw1f[nf*4+r] = 0.f;
        s_w1[hr*520 + dcol] = f2bf(a);
        float c = iw2[(size_t)(d0 + hr)*LWW + dcol];
        w2f[nf*4+r] = c; mw2f[nf*4+r] = 0.f;
        s_w2[hr*520 + dcol] = f2bf(c);
        pk[r] = f2bf(c);
      }
      *(u16x4*)(w2T1 + (size_t)(wid*64 + nf*16 + l15)*DD + d0 + q*4) = pk;
    }
    if (tid < 16){
      s_b1[tid] = ib1[h0 + tid]; s_mb1[tid] = 0.f;
      s_b2[tid] = ib2[d0 + tid]; s_mb2[tid] = 0.f;
    }
#pragma unroll
    for (int r = 0; r < 4; ++r) actr[r] = 0.f;
    __syncthreads();
  }

  for (int t = 0; t < NCH; ++t){
    // ======== PHASE A ========
    if (t > 0){
      // preload g_w1 B-fragments (KT rows d, cols c of chunk t-1)
      fragAB kfr[8];
#pragma unroll
      for (int nf = 0; nf < 4; ++nf)
#pragma unroll
        for (int kk = 0; kk < 2; ++kk)
          kfr[nf*2+kk] = frag_bf16g(KTbat + (size_t)(t-1)*CC, SS, wid*64 + nf*16, kk*32, lane);

      // dh (waves 0-3): [64 c][16 h] = dvp @ w2T(pre-chunk-(t-1))
      if (wid < 4){
        const u16* w2T = w2Tb + (size_t)(t&1)*W2TBUF + (size_t)b*DD*LWW;
        fragC a0 = zeroC();
        for (int k0 = 0; k0 < DD; k0 += 32)
          a0 = MFMA16(frag_bf16g(dv_b, DD, wid*16, k0, lane),
                      frag_bf16g(w2T, DD, h0, k0, lane), a0);
#pragma unroll
        for (int r = 0; r < 4; ++r)
          s_t[l15*72 + wid*16 + q*4 + r] = f2bf(a0[r] * actr[r]);
      }
      __syncthreads();

      // g_w1 [16 h][512 d], K = 64 c
      fragC ag[4];
#pragma unroll
      for (int i = 0; i < 4; ++i) ag[i] = zeroC();
#pragma unroll
      for (int kk = 0; kk < 2; ++kk){
        fragAB af = frag_lds(s_t, 72, 0, kk*32, lane);
#pragma unroll
        for (int nf = 0; nf < 4; ++nf)
          ag[nf] = MFMA16(af, kfr[nf*2+kk], ag[nf]);
      }
      const float* g3 = aet + ((size_t)b*NCH + (t-1)) * 3;
      float ga = g3[0], ge = g3[1], gth = g3[2];
#pragma unroll
      for (int nf = 0; nf < 4; ++nf)
#pragma unroll
        for (int r = 0; r < 4; ++r){
          float g  = ag[nf][r] * (1.f/64.f);
          float m_ = ge*mw1f[nf*4+r] - gth*g;
          float w_ = (1.f-ga)*w1f[nf*4+r] + m_;
          mw1f[nf*4+r] = m_; w1f[nf*4+r] = w_;
          s_w1[(q*4+r)*520 + wid*64 + nf*16 + l15] = f2bf(w_);
        }
      if (tid < 16){
        float s = 0.f;
        for (int c = 0; c < CC; ++c) s += bf2f(s_t[tid*72 + c]);
        float gb = s * (1.f/64.f);
        float m_ = ge*s_mb1[tid] - gth*gb;
        float bn = (1.f-ga)*s_b1[tid] + m_;
        s_mb1[tid] = m_; s_b1[tid] = bn;
      }
      __syncthreads();
    }

    // pre (waves 0-3, K-input) & hq (waves 4-7, Q-input) for chunk t
    {
      const u16* Ac = (wid < 4 ? Kball : Qball) + (size_t)t*CC*DD;
      int m0 = (wid & 3) * 16;
      fragC acc = zeroC();
      for (int k0 = 0; k0 < DD; k0 += 32)
        acc = MFMA16(frag_bf16g(Ac, DD, m0, k0, lane),
                     frag_lds(s_w1, 520, 0, k0, lane), acc);
      float bb = s_b1[l15];
      if (wid < 4){
        u16x4 pk;
#pragma unroll
        for (int r = 0; r < 4; ++r){
          int c = m0 + q*4 + r;
          float pre = acc[r] + bb;
          float sg  = 1.f/(1.f+expf(-pre));
          float hkv = pre * sg;
          actr[r]   = sg * (1.f + pre * (1.f - sg));
          short hb  = f2bf(hkv);
          hk_b[(size_t)c*LWW + h0 + l15] = (u16)hb;
          pk[r] = hb;
        }
        *(u16x4*)(hkT_b + (size_t)(h0 + l15)*CC + m0 + q*4) = pk;
      } else {
#pragma unroll
        for (int r = 0; r < 4; ++r){
          int c = m0 + q*4 + r;
          float hqv = acc[r] + bb;
          float s2  = 1.f/(1.f+expf(-hqv));
          hq_b[(size_t)c*LWW + h0 + l15] = (u16)f2bf(hqv * s2);
        }
      }
    }
    tgt += 32; batchbar(bar, tgt);

    // ======== PHASE B ========
    // preload g_w2 B-fragments (hkT rows h, cols c)
    fragAB hfr[8];
#pragma unroll
    for (int nf = 0; nf < 4; ++nf)
#pragma unroll
      for (int kk = 0; kk < 2; ++kk)
        hfr[nf*2+kk] = frag_bf16g(hkT_b, CC, wid*64 + nf*16, kk*32, lane);

    // y (waves 0-3) / vp (waves 4-7): [64 c][16 d-tile], K = 512 h
    {
      const u16* Ah = (wid < 4) ? hq_b : hk_b;
      int m0 = (wid & 3) * 16;
      fragC acc = zeroC();
      for (int k0 = 0; k0 < LWW; k0 += 32)
        acc = MFMA16(frag_bf16g(Ah, LWW, m0, k0, lane),
                     frag_lds(s_w2, 520, 0, k0, lane), acc);
      float bb = s_b2[l15];
      if (wid < 4){
#pragma unroll
        for (int r = 0; r < 4; ++r){
          int c = m0 + q*4 + r;
          out[((size_t)b*SS + (size_t)t*CC + c)*DD + d0 + l15] = acc[r] + bb;
        }
      } else {
#pragma unroll
        for (int r = 0; r < 4; ++r){
          int c = m0 + q*4 + r;
          size_t oi = ((size_t)b*SS + (size_t)t*CC + c)*DD + d0 + l15;
          float dvv = (acc[r] + bb - V[oi]) * (2.f/512.f);
          short db_ = f2bf(dvv);
          dv_b[(size_t)c*DD + d0 + l15] = (u16)db_;
          s_t[l15*72 + c] = db_;
        }
      }
    }
    __syncthreads();

    // g_w2 [16 d][512 h], K = 64 c ; update w2/mw2/b2; write s_w2 + w2T buf[(t+1)&1]
    {
      fragC ag[4];
#pragma unroll
      for (int i = 0; i < 4; ++i) ag[i] = zeroC();
#pragma unroll
      for (int kk = 0; kk < 2; ++kk){
        fragAB af = frag_lds(s_t, 72, 0, kk*32, lane);
#pragma unroll
        for (int nf = 0; nf < 4; ++nf)
          ag[nf] = MFMA16(af, hfr[nf*2+kk], ag[nf]);
      }
      const float* g3 = aet + ((size_t)b*NCH + t) * 3;
      float ga = g3[0], ge = g3[1], gth = g3[2];
      u16* w2Tn = w2Tb + (size_t)((t+1)&1)*W2TBUF + (size_t)b*DD*LWW;
#pragma unroll
      for (int nf = 0; nf < 4; ++nf){
        u16x4 pk;
#pragma unroll
        for (int r = 0; r < 4; ++r){
          float g  = ag[nf][r] * (1.f/64.f);
          float m_ = ge*mw2f[nf*4+r] - gth*g;
          float w_ = (1.f-ga)*w2f[nf*4+r] + m_;
          mw2f[nf*4+r] = m_; w2f[nf*4+r] = w_;
          short wb = f2bf(w_);
          s_w2[(q*4+r)*520 + wid*64 + nf*16 + l15] = wb;
          pk[r] = wb;
        }
        *(u16x4*)(w2Tn + (size_t)(wid*64 + nf*16 + l15)*DD + d0 + q*4) = pk;
      }
      if (tid < 16){
        float s = 0.f;
        for (int c = 0; c < CC; ++c) s += bf2f(s_t[tid*72 + c]);
        float gb = s * (1.f/64.f);
        float m_ = ge*s_mb2[tid] - gth*gb;
        float bn = (1.f-ga)*s_b2[tid] + m_;
        s_mb2[tid] = m_; s_b2[tid] = bn;
      }
    }
    tgt += 32; batchbar(bar, tgt);
  }
}

extern "C" void kernel_launch(void* const* d_in, const int* in_sizes, int n_in,
                              void* d_out, int out_size, void* d_ws, size_t ws_size,
                              hipStream_t stream){
  const float* x   = (const float*)d_in[0];
  const float* Wq  = (const float*)d_in[1];
  const float* Wk  = (const float*)d_in[2];
  const float* Wv  = (const float*)d_in[3];
  const float* iw1 = (const float*)d_in[4];
  const float* ib1 = (const float*)d_in[5];
  const float* iw2 = (const float*)d_in[6];
  const float* ib2 = (const float*)d_in[7];
  const float* aw  = (const float*)d_in[8];
  const float* ab  = (const float*)d_in[9];
  const float* ew  = (const float*)d_in[10];
  const float* eb  = (const float*)d_in[11];
  const float* tw  = (const float*)d_in[12];
  const float* tb  = (const float*)d_in[13];
  float* out = (float*)d_out;

  float* fw = (float*)d_ws;
  float* V    = fw;  fw += (size_t)BB*SS*DD;
  float* aet  = fw;  fw += (size_t)BB*NCH*3 + 61;
  unsigned* bar = (unsigned*)fw; fw += 128;
  u16* xb   = (u16*)fw;                       // aliased as KTg after k_proj
  u16* Wc   = xb   + (size_t)BB*SS*DD;
  u16* Qb   = Wc   + (size_t)3*DD*DD;
  u16* Kb   = Qb   + (size_t)BB*SS*DD;
  u16* hkb  = Kb   + (size_t)BB*SS*DD;
  u16* hqs  = hkb  + (size_t)BB*CC*LWW;
  u16* hkT  = hqs  + (size_t)BB*CC*LWW;
  u16* dvpb = hkT  + (size_t)BB*LWW*CC;
  u16* w2Tb = dvpb + (size_t)BB*CC*DD;        // 2 buffers of BB*DD*LWW
  u16* KTg  = xb;

  k_cvt  <<<8960, 256, 0, stream>>>(x, Wq, Wk, Wv, xb, Wc, bar);
  k_proj <<<3072, 256, 0, stream>>>(xb, Wc, Qb, Kb, V);
  k_norm <<<8192, 256, 0, stream>>>(Qb, Kb);
  k_trans<<<2048, 256, 0, stream>>>(Kb, KTg);
  k_gates<<<256,  256, 0, stream>>>(x, aw, ab, ew, eb, tw, tb, aet);
  k_scan <<<128,  512, 0, stream>>>(Qb, Kb, KTg, V, aet, iw1, ib1, iw2, ib2,
                                    hkb, hqs, hkT, dvpb, w2Tb, out, bar);
}

// Round 4
// 1803.337 us; speedup vs baseline: 3.9392x; 3.2081x over previous
//
#include <hip/hip_runtime.h>
#include <hip/hip_bf16.h>

#define BB 4
#define SS 4096
#define DD 512
#define LWW 512
#define CC 64
#define NCH 64

typedef unsigned short u16;
using fragAB = __attribute__((ext_vector_type(8))) short;
using fragC  = __attribute__((ext_vector_type(4))) float;
using u16x4  = __attribute__((ext_vector_type(4))) short;

__device__ __forceinline__ short f2bf(float f){
  unsigned u = __float_as_uint(f);
  u = (u + 0x7FFFu + ((u >> 16) & 1u)) >> 16;
  return (short)u;
}
__device__ __forceinline__ float bf2f(short s){
  return __uint_as_float(((unsigned)(u16)s) << 16);
}
__device__ __forceinline__ fragC zeroC(){ fragC z = {0.f,0.f,0.f,0.f}; return z; }

__device__ __forceinline__ fragAB frag_bf16g(const u16* __restrict__ base, int ld, int r0, int k0, int lane){
  return *(const fragAB*)(base + (size_t)(r0 + (lane & 15)) * ld + k0 + ((lane >> 4) << 3));
}
__device__ __forceinline__ fragAB frag_lds(const short* base, int ld, int r0, int k0, int lane){
  return *(const fragAB*)(base + (r0 + (lane & 15)) * ld + k0 + ((lane >> 4) << 3));
}
#define MFMA16(a,b,c) __builtin_amdgcn_mfma_f32_16x16x32_bf16(a,b,c,0,0,0)

// ---- system-coherent (Infinity-Cache) access: bypass L1+L2 on both sides ----
__device__ __forceinline__ void ld_sys(fragAB& r, const u16* p){
  asm volatile("global_load_dwordx4 %0, %1, off sc0 sc1" : "=v"(r) : "v"(p));
}
__device__ __forceinline__ void st_sys2(u16* p, short v){
  asm volatile("global_store_short %0, %1, off sc0 sc1" :: "v"(p), "v"((unsigned)(u16)v));
}
__device__ __forceinline__ void st_sys8(u16* p, u16x4 v){
  asm volatile("global_store_dwordx2 %0, %1, off sc0 sc1" :: "v"(p), "v"(v));
}
#define WAITVM(N) do { asm volatile("s_waitcnt vmcnt(" #N ")" ::: "memory"); \
                       __builtin_amdgcn_sched_barrier(0); } while (0)

// tiled exchange layout [k/16][64 c][16]: addr(c, kq) ; kq = k + (sub-offset), kq&15 in {0,8}
__device__ __forceinline__ const u16* taddr(const u16* base, int c, int kq){
  return base + (((size_t)((kq >> 4)*64 + c)) << 4) + (kq & 15);
}
__device__ __forceinline__ u16* taddrw(u16* base, int c, int kq){
  return base + (((size_t)((kq >> 4)*64 + c)) << 4) + (kq & 15);
}

// ---------------- per-batch barrier: relaxed atomics, no cache fences ----------------
__device__ __forceinline__ void batchbar(unsigned* bar, unsigned target){
  asm volatile("s_waitcnt vmcnt(0)" ::: "memory");
  __syncthreads();
  if (threadIdx.x == 0){
    __hip_atomic_fetch_add(bar, 1u, __ATOMIC_RELAXED, __HIP_MEMORY_SCOPE_AGENT);
    while (__hip_atomic_load(bar, __ATOMIC_RELAXED, __HIP_MEMORY_SCOPE_AGENT) < target)
      __builtin_amdgcn_s_sleep(2);
  }
  __syncthreads();
}

// ---------------- fp32 -> bf16 conversions (x, W concat) + bar zero ----------------
__global__ __launch_bounds__(256) void k_cvt(const float* __restrict__ x,
    const float* __restrict__ Wq, const float* __restrict__ Wk, const float* __restrict__ Wv,
    u16* __restrict__ xb, u16* __restrict__ Wc, unsigned* __restrict__ bar){
  size_t i = (size_t)blockIdx.x * 256 + threadIdx.x;
  if (blockIdx.x == 0 && threadIdx.x < 128) bar[threadIdx.x] = 0u;
  const size_t NX4 = (size_t)BB*SS*DD/4;
  const size_t NW4 = (size_t)DD*DD/4;
  if (i < NX4){
    float4 v = ((const float4*)x)[i];
    u16x4 o = { f2bf(v.x), f2bf(v.y), f2bf(v.z), f2bf(v.w) };
    *(u16x4*)(xb + 4*i) = o;
  } else if (i < NX4 + 3*NW4){
    size_t j = i - NX4;
    const float* src = (j < NW4) ? Wq : (j < 2*NW4) ? Wk : Wv;
    size_t jj = j % NW4;
    float4 v = ((const float4*)src)[jj];
    u16x4 o = { f2bf(v.x), f2bf(v.y), f2bf(v.z), f2bf(v.w) };
    *(u16x4*)(Wc + 4*j) = o;
  }
}

// ---------------- Q,K,V projections (bf16 inputs) ----------------
__global__ __launch_bounds__(256) void k_proj(const u16* __restrict__ xb,
    const u16* __restrict__ Wc,
    u16* __restrict__ Qb, u16* __restrict__ Kb, float* __restrict__ V){
  int mt = blockIdx.x / 12, nt = blockIdx.x % 12;
  int lane = threadIdx.x & 63, wid = threadIdx.x >> 6;
  int m0 = mt * 64 + wid * 16;
  const u16* Bp = Wc + (size_t)nt * 128 * DD;
  fragC acc[8];
#pragma unroll
  for (int i = 0; i < 8; ++i) acc[i] = zeroC();
  for (int k0 = 0; k0 < DD; k0 += 32){
    fragAB a = frag_bf16g(xb, DD, m0, k0, lane);
#pragma unroll
    for (int nf = 0; nf < 8; ++nf)
      acc[nf] = MFMA16(a, frag_bf16g(Bp, DD, nf*16, k0, lane), acc[nf]);
  }
#pragma unroll
  for (int nf = 0; nf < 8; ++nf){
#pragma unroll
    for (int r = 0; r < 4; ++r){
      int m = m0 + ((lane >> 4) << 2) + r;
      int col = nt*128 + nf*16 + (lane & 15);
      float v = acc[nf][r];
      if (nt < 4)      Qb[(size_t)m*DD + col]        = (u16)f2bf(v);
      else if (nt < 8) Kb[(size_t)m*DD + col - 512]  = (u16)f2bf(v);
      else             V [(size_t)m*DD + col - 1024] = v;
    }
  }
}

// ---------------- l2-normalize Q,K rows in place ----------------
__global__ __launch_bounds__(256) void k_norm(u16* __restrict__ Qb, u16* __restrict__ Kb){
  int idx = blockIdx.x * 4 + (threadIdx.x >> 6);
  int lane = threadIdx.x & 63;
  u16* p = (idx < BB*SS ? Qb + (size_t)idx * DD
                        : Kb + (size_t)(idx - BB*SS) * DD) + lane * 8;
  fragAB v = *(const fragAB*)p;
  float f[8]; float s = 0.f;
#pragma unroll
  for (int i = 0; i < 8; ++i){ f[i] = bf2f(v[i]); s += f[i]*f[i]; }
#pragma unroll
  for (int o = 32; o > 0; o >>= 1) s += __shfl_xor(s, o, 64);
  float inv = 1.f / fmaxf(sqrtf(s), 1e-12f);
  fragAB o8;
#pragma unroll
  for (int i = 0; i < 8; ++i) o8[i] = f2bf(f[i] * inv);
  *(fragAB*)p = o8;
}

// ---------------- transpose K: Kb[b*S][D] -> KT[b][D][S] ----------------
__global__ __launch_bounds__(256) void k_trans(const u16* __restrict__ Kb, u16* __restrict__ KT){
  __shared__ short tile[64][68];
  int blk = blockIdx.x;
  int b = blk >> 9, rem = blk & 511;
  int st = rem >> 3, dt = rem & 7;
  int s0 = st*64, d0 = dt*64;
  int sr = threadIdx.x & 63, q = threadIdx.x >> 6;
  const u16* src = Kb + ((size_t)b*SS + s0 + sr)*DD + d0 + q*16;
  fragAB v0 = *(const fragAB*)src;
  fragAB v1 = *(const fragAB*)(src + 8);
#pragma unroll
  for (int i = 0; i < 8; ++i){ tile[sr][q*16+i] = v0[i]; tile[sr][q*16+8+i] = v1[i]; }
  __syncthreads();
  fragAB o0, o1;
#pragma unroll
  for (int i = 0; i < 8; ++i){ o0[i] = tile[q*16+i][sr]; o1[i] = tile[q*16+8+i][sr]; }
  u16* dst = KT + ((size_t)b*DD + d0 + sr)*SS + s0 + q*16;
  *(fragAB*)dst = o0;
  *(fragAB*)(dst + 8) = o1;
}

// ---------------- gates a,e,theta per (batch, chunk) ----------------
__global__ __launch_bounds__(256) void k_gates(const float* __restrict__ x,
    const float* __restrict__ aw, const float* __restrict__ ab,
    const float* __restrict__ ew, const float* __restrict__ eb,
    const float* __restrict__ tw, const float* __restrict__ tb,
    float* __restrict__ aet){
  __shared__ float part[64][4][3];
  __shared__ float rowsig[64][3];
  int b = blockIdx.x >> 6, t = blockIdx.x & 63;
  int tid = threadIdx.x;
  int r = tid >> 2, p = tid & 3;
  const float4* xp = (const float4*)(x + ((size_t)b*SS + (size_t)t*CC + r) * DD + p * 128);
  const float4* a4 = (const float4*)(aw + p*128);
  const float4* e4 = (const float4*)(ew + p*128);
  const float4* t4 = (const float4*)(tw + p*128);
  float s0 = 0.f, s1 = 0.f, s2 = 0.f;
  for (int i = 0; i < 32; ++i){
    float4 xv = xp[i], av = a4[i], ev = e4[i], tv = t4[i];
    s0 += xv.x*av.x + xv.y*av.y + xv.z*av.z + xv.w*av.w;
    s1 += xv.x*ev.x + xv.y*ev.y + xv.z*ev.z + xv.w*ev.w;
    s2 += xv.x*tv.x + xv.y*tv.y + xv.z*tv.z + xv.w*tv.w;
  }
  part[r][p][0] = s0; part[r][p][1] = s1; part[r][p][2] = s2;
  __syncthreads();
  if (tid < 64){
    float a_ = part[tid][0][0]+part[tid][1][0]+part[tid][2][0]+part[tid][3][0] + ab[0];
    float e_ = part[tid][0][1]+part[tid][1][1]+part[tid][2][1]+part[tid][3][1] + eb[0];
    float t_ = part[tid][0][2]+part[tid][1][2]+part[tid][2][2]+part[tid][3][2] + tb[0];
    rowsig[tid][0] = 1.f/(1.f+expf(-a_));
    rowsig[tid][1] = 1.f/(1.f+expf(-e_));
    rowsig[tid][2] = 1.f/(1.f+expf(-t_));
  }
  __syncthreads();
  if (tid < 3){
    float s = 0.f;
    for (int i = 0; i < 64; ++i) s += rowsig[i][tid];
    aet[((size_t)b*NCH + t)*3 + tid] = s * (1.f/64.f);
  }
}

// ---------------- persistent fused scan: state in registers, IC-coherent exchange ----------------
__global__ __launch_bounds__(512, 2) void k_scan(
    const u16* __restrict__ Qb, const u16* __restrict__ Kb, const u16* __restrict__ KTg,
    const float* __restrict__ V, const float* __restrict__ aet,
    const float* __restrict__ iw1, const float* __restrict__ ib1,
    const float* __restrict__ iw2, const float* __restrict__ ib2,
    u16* __restrict__ hkb, u16* __restrict__ hqs, u16* __restrict__ hkT,
    u16* __restrict__ dvpb, u16* __restrict__ w2Tb,
    float* __restrict__ out, unsigned* __restrict__ barb)
{
  __shared__ __align__(16) short s_w1[16*520];
  __shared__ __align__(16) short s_w2[16*520];
  __shared__ __align__(16) short s_t[16*72];
  __shared__ float s_b1[16], s_mb1[16], s_b2[16], s_mb2[16];

  const int tid  = threadIdx.x;
  const int lane = tid & 63;
  const int wid  = tid >> 6;
  const int q    = lane >> 4;
  const int l15  = lane & 15;
  const int b    = (blockIdx.x & 7) >> 1;
  const int tl   = ((blockIdx.x >> 3) << 1) | (blockIdx.x & 1);
  const int h0   = tl * 16;
  const int d0   = tl * 16;
  unsigned* bar  = barb + b * 32;
  unsigned  tgt  = 0;

  const u16* Kball = Kb  + (size_t)b*SS*DD;
  const u16* Qball = Qb  + (size_t)b*SS*DD;
  const u16* KTbat = KTg + (size_t)b*DD*SS;
  u16* hk_b  = hkb  + (size_t)b*CC*LWW;    // tiled [32][64][16]
  u16* hq_b  = hqs  + (size_t)b*CC*LWW;    // tiled [32][64][16]
  u16* hkT_b = hkT  + (size_t)b*LWW*CC;    // [h][64 c]
  u16* dv_b  = dvpb + (size_t)b*CC*DD;     // tiled [32][64][16]
  const size_t W2TBUF = (size_t)BB*DD*LWW;

  float w1f[16], mw1f[16], w2f[16], mw2f[16], actr[4];

  // ---- preamble: init state; initial w2T -> buf[0] ----
  {
    u16* w2T0 = w2Tb + (size_t)b*DD*LWW;
#pragma unroll
    for (int nf = 0; nf < 4; ++nf){
      u16x4 pk;
#pragma unroll
      for (int r = 0; r < 4; ++r){
        int hr = q*4 + r;
        int dcol = wid*64 + nf*16 + l15;
        float a = iw1[(size_t)(h0 + hr)*DD + dcol];
        w1f[nf*4+r] = a; mw1f[nf*4+r] = 0.f;
        s_w1[hr*520 + dcol] = f2bf(a);
        float c = iw2[(size_t)(d0 + hr)*LWW + dcol];
        w2f[nf*4+r] = c; mw2f[nf*4+r] = 0.f;
        s_w2[hr*520 + dcol] = f2bf(c);
        pk[r] = f2bf(c);
      }
      st_sys8(w2T0 + (size_t)(wid*64 + nf*16 + l15)*DD + d0 + q*4, pk);
    }
    if (tid < 16){
      s_b1[tid] = ib1[h0 + tid]; s_mb1[tid] = 0.f;
      s_b2[tid] = ib2[d0 + tid]; s_mb2[tid] = 0.f;
    }
#pragma unroll
    for (int r = 0; r < 4; ++r) actr[r] = 0.f;
    __syncthreads();
  }

  for (int t = 0; t < NCH; ++t){
    // ======== PHASE A ========
    if (t > 0){
      // cached preload of g_w1 B-fragments (KT, chunk t-1)
      fragAB kfr[8];
      {
        const u16* KT = KTbat + (size_t)(t-1)*CC;
#pragma unroll
        for (int nf = 0; nf < 4; ++nf)
#pragma unroll
          for (int kk = 0; kk < 2; ++kk)
            kfr[nf*2+kk] = frag_bf16g(KT, SS, wid*64 + nf*16, kk*32, lane);
      }
      // dh (waves 0-3): [64 c][16 h] = dvp @ w2T(entering step t-1), pipelined system loads
      if (wid < 4){
        const u16* w2T = w2Tb + (size_t)((t+1)&1)*W2TBUF + (size_t)b*DD*LWW;
        fragC a0 = zeroC();
        fragAB fa[4], fb[4], sa[4], sb[4];
        int qk = (q << 3);
#pragma unroll
        for (int j = 0; j < 4; ++j){
          int k0 = j*32;
          ld_sys(fa[j], taddr(dv_b, wid*16 + l15, k0 + qk));
          ld_sys(fb[j], w2T + (size_t)(h0 + l15)*DD + k0 + qk);
        }
#pragma unroll
        for (int j = 0; j < 4; ++j){
          int k0 = 128 + j*32;
          ld_sys(sa[j], taddr(dv_b, wid*16 + l15, k0 + qk));
          ld_sys(sb[j], w2T + (size_t)(h0 + l15)*DD + k0 + qk);
        }
        WAITVM(8);
#pragma unroll
        for (int j = 0; j < 4; ++j) a0 = MFMA16(fa[j], fb[j], a0);
#pragma unroll
        for (int j = 0; j < 4; ++j){
          int k0 = 256 + j*32;
          ld_sys(fa[j], taddr(dv_b, wid*16 + l15, k0 + qk));
          ld_sys(fb[j], w2T + (size_t)(h0 + l15)*DD + k0 + qk);
        }
        WAITVM(8);
#pragma unroll
        for (int j = 0; j < 4; ++j) a0 = MFMA16(sa[j], sb[j], a0);
#pragma unroll
        for (int j = 0; j < 4; ++j){
          int k0 = 384 + j*32;
          ld_sys(sa[j], taddr(dv_b, wid*16 + l15, k0 + qk));
          ld_sys(sb[j], w2T + (size_t)(h0 + l15)*DD + k0 + qk);
        }
        WAITVM(8);
#pragma unroll
        for (int j = 0; j < 4; ++j) a0 = MFMA16(fa[j], fb[j], a0);
        WAITVM(0);
#pragma unroll
        for (int j = 0; j < 4; ++j) a0 = MFMA16(sa[j], sb[j], a0);
#pragma unroll
        for (int r = 0; r < 4; ++r)
          s_t[l15*72 + wid*16 + q*4 + r] = f2bf(a0[r] * actr[r]);
      }
      __syncthreads();
      // g_w1 [16 h][512 d], K = 64 c
      {
        fragC ag[4];
#pragma unroll
        for (int i = 0; i < 4; ++i) ag[i] = zeroC();
#pragma unroll
        for (int kk = 0; kk < 2; ++kk){
          fragAB af = frag_lds(s_t, 72, 0, kk*32, lane);
#pragma unroll
          for (int nf = 0; nf < 4; ++nf)
            ag[nf] = MFMA16(af, kfr[nf*2+kk], ag[nf]);
        }
        const float* g3 = aet + ((size_t)b*NCH + (t-1)) * 3;
        float ga = g3[0], ge = g3[1], gth = g3[2];
#pragma unroll
        for (int nf = 0; nf < 4; ++nf)
#pragma unroll
          for (int r = 0; r < 4; ++r){
            float g  = ag[nf][r] * (1.f/64.f);
            float m_ = ge*mw1f[nf*4+r] - gth*g;
            float w_ = (1.f-ga)*w1f[nf*4+r] + m_;
            mw1f[nf*4+r] = m_; w1f[nf*4+r] = w_;
            s_w1[(q*4+r)*520 + wid*64 + nf*16 + l15] = f2bf(w_);
          }
        if (tid < 16){
          float s = 0.f;
          for (int c = 0; c < CC; ++c) s += bf2f(s_t[tid*72 + c]);
          float gb = s * (1.f/64.f);
          float m_ = ge*s_mb1[tid] - gth*gb;
          float bn = (1.f-ga)*s_b1[tid] + m_;
          s_mb1[tid] = m_; s_b1[tid] = bn;
        }
      }
    }
    __syncthreads();
    // pre (waves 0-3, K) & hq (waves 4-7, Q) for chunk t  [cached A, LDS B]
    {
      const u16* Ac = (wid < 4 ? Kball : Qball) + (size_t)t*CC*DD;
      int m0 = (wid & 3) * 16;
      fragC acc = zeroC();
      for (int k0 = 0; k0 < DD; k0 += 32)
        acc = MFMA16(frag_bf16g(Ac, DD, m0, k0, lane),
                     frag_lds(s_w1, 520, 0, k0, lane), acc);
      float bb = s_b1[l15];
      if (wid < 4){
        u16x4 pk;
#pragma unroll
        for (int r = 0; r < 4; ++r){
          int c = m0 + q*4 + r;
          float pre = acc[r] + bb;
          float sg  = 1.f/(1.f+expf(-pre));
          float hkv = pre * sg;
          actr[r]   = sg * (1.f + pre * (1.f - sg));
          short hb  = f2bf(hkv);
          st_sys2(taddrw(hk_b, c, h0 + l15), hb);
          pk[r] = hb;
        }
        st_sys8(hkT_b + (size_t)(h0 + l15)*CC + m0 + q*4, pk);
      } else {
#pragma unroll
        for (int r = 0; r < 4; ++r){
          int c = m0 + q*4 + r;
          float hqv = acc[r] + bb;
          float s2  = 1.f/(1.f+expf(-hqv));
          st_sys2(taddrw(hq_b, c, h0 + l15), f2bf(hqv * s2));
        }
      }
    }
    tgt += 32; batchbar(bar, tgt);

    // ======== PHASE B ========
    {
      const u16* Ah = (wid < 4) ? hq_b : hk_b;
      int m0 = (wid & 3) * 16;
      int qk = (q << 3);
      fragC acc = zeroC();
      fragAB va[4], vb[4], hfr[8];
      // prefetch V (cached) early for the dvp epilogue
      float vv[4];
      if (wid >= 4){
#pragma unroll
        for (int r = 0; r < 4; ++r)
          vv[r] = V[((size_t)b*SS + (size_t)t*CC + m0 + q*4 + r)*DD + d0 + l15];
      }
#pragma unroll
      for (int j = 0; j < 4; ++j) ld_sys(va[j], taddr(Ah, m0 + l15, j*32 + qk));
#pragma unroll
      for (int j = 0; j < 4; ++j) ld_sys(vb[j], taddr(Ah, m0 + l15, 128 + j*32 + qk));
      WAITVM(4);
#pragma unroll
      for (int j = 0; j < 4; ++j) acc = MFMA16(va[j], frag_lds(s_w2, 520, 0, j*32, lane), acc);
#pragma unroll
      for (int j = 0; j < 4; ++j) ld_sys(va[j], taddr(Ah, m0 + l15, 256 + j*32 + qk));
      WAITVM(4);
#pragma unroll
      for (int j = 0; j < 4; ++j) acc = MFMA16(vb[j], frag_lds(s_w2, 520, 128 + j*32 >= 0 ? 0 : 0, 128 + j*32, lane), acc);
#pragma unroll
      for (int j = 0; j < 4; ++j) ld_sys(vb[j], taddr(Ah, m0 + l15, 384 + j*32 + qk));
      WAITVM(4);
#pragma unroll
      for (int j = 0; j < 4; ++j) acc = MFMA16(va[j], frag_lds(s_w2, 520, 0, 256 + j*32, lane), acc);
      // g_w2 B-fragments (hkT) — system loads, consumed after next sync
#pragma unroll
      for (int nf = 0; nf < 4; ++nf)
#pragma unroll
        for (int kk = 0; kk < 2; ++kk)
          ld_sys(hfr[nf*2+kk], hkT_b + (size_t)(wid*64 + nf*16 + l15)*CC + kk*32 + qk);
      WAITVM(8);
#pragma unroll
      for (int j = 0; j < 4; ++j) acc = MFMA16(vb[j], frag_lds(s_w2, 520, 0, 384 + j*32, lane), acc);

      float bb = s_b2[l15];
      if (wid < 4){
#pragma unroll
        for (int r = 0; r < 4; ++r){
          int c = m0 + q*4 + r;
          __builtin_nontemporal_store(acc[r] + bb,
            &out[((size_t)b*SS + (size_t)t*CC + c)*DD + d0 + l15]);
        }
      } else {
#pragma unroll
        for (int r = 0; r < 4; ++r){
          int c = m0 + q*4 + r;
          float dvv = (acc[r] + bb - vv[r]) * (2.f/512.f);
          short db_ = f2bf(dvv);
          st_sys2(taddrw(dv_b, c, d0 + l15), db_);
          s_t[l15*72 + c] = db_;
        }
      }
      __syncthreads();
      // g_w2 [16 d][512 h], K = 64 c
      WAITVM(0);
      fragC ag[4];
#pragma unroll
      for (int i = 0; i < 4; ++i) ag[i] = zeroC();
#pragma unroll
      for (int kk = 0; kk < 2; ++kk){
        fragAB af = frag_lds(s_t, 72, 0, kk*32, lane);
#pragma unroll
        for (int nf = 0; nf < 4; ++nf)
          ag[nf] = MFMA16(af, hfr[nf*2+kk], ag[nf]);
      }
      const float* g3 = aet + ((size_t)b*NCH + t) * 3;
      float ga = g3[0], ge = g3[1], gth = g3[2];
      u16* w2Tn = w2Tb + (size_t)((t+1)&1)*W2TBUF + (size_t)b*DD*LWW;
#pragma unroll
      for (int nf = 0; nf < 4; ++nf){
        u16x4 pk;
#pragma unroll
        for (int r = 0; r < 4; ++r){
          float g  = ag[nf][r] * (1.f/64.f);
          float m_ = ge*mw2f[nf*4+r] - gth*g;
          float w_ = (1.f-ga)*w2f[nf*4+r] + m_;
          mw2f[nf*4+r] = m_; w2f[nf*4+r] = w_;
          short wb = f2bf(w_);
          s_w2[(q*4+r)*520 + wid*64 + nf*16 + l15] = wb;
          pk[r] = wb;
        }
        st_sys8(w2Tn + (size_t)(wid*64 + nf*16 + l15)*DD + d0 + q*4, pk);
      }
      if (tid < 16){
        float s = 0.f;
        for (int c2 = 0; c2 < CC; ++c2) s += bf2f(s_t[tid*72 + c2]);
        float gb = s * (1.f/64.f);
        float m_ = ge*s_mb2[tid] - gth*gb;
        float bn = (1.f-ga)*s_b2[tid] + m_;
        s_mb2[tid] = m_; s_b2[tid] = bn;
      }
    }
    tgt += 32; batchbar(bar, tgt);
  }
}

extern "C" void kernel_launch(void* const* d_in, const int* in_sizes, int n_in,
                              void* d_out, int out_size, void* d_ws, size_t ws_size,
                              hipStream_t stream){
  const float* x   = (const float*)d_in[0];
  const float* Wq  = (const float*)d_in[1];
  const float* Wk  = (const float*)d_in[2];
  const float* Wv  = (const float*)d_in[3];
  const float* iw1 = (const float*)d_in[4];
  const float* ib1 = (const float*)d_in[5];
  const float* iw2 = (const float*)d_in[6];
  const float* ib2 = (const float*)d_in[7];
  const float* aw  = (const float*)d_in[8];
  const float* ab  = (const float*)d_in[9];
  const float* ew  = (const float*)d_in[10];
  const float* eb  = (const float*)d_in[11];
  const float* tw  = (const float*)d_in[12];
  const float* tb  = (const float*)d_in[13];
  float* out = (float*)d_out;

  float* fw = (float*)d_ws;
  float* V    = fw;  fw += (size_t)BB*SS*DD;
  float* aet  = fw;  fw += (size_t)BB*NCH*3 + 61;
  unsigned* bar = (unsigned*)fw; fw += 128;
  u16* xb   = (u16*)fw;                       // aliased as KTg after k_proj
  u16* Wc   = xb   + (size_t)BB*SS*DD;
  u16* Qb   = Wc   + (size_t)3*DD*DD;
  u16* Kb   = Qb   + (size_t)BB*SS*DD;
  u16* hkb  = Kb   + (size_t)BB*SS*DD;
  u16* hqs  = hkb  + (size_t)BB*CC*LWW;
  u16* hkT  = hqs  + (size_t)BB*CC*LWW;
  u16* dvpb = hkT  + (size_t)BB*LWW*CC;
  u16* w2Tb = dvpb + (size_t)BB*CC*DD;        // 2 buffers of BB*DD*LWW
  u16* KTg  = xb;

  k_cvt  <<<8960, 256, 0, stream>>>(x, Wq, Wk, Wv, xb, Wc, bar);
  k_proj <<<3072, 256, 0, stream>>>(xb, Wc, Qb, Kb, V);
  k_norm <<<8192, 256, 0, stream>>>(Qb, Kb);
  k_trans<<<2048, 256, 0, stream>>>(Kb, KTg);
  k_gates<<<256,  256, 0, stream>>>(x, aw, ab, ew, eb, tw, tb, aet);
  k_scan <<<128,  512, 0, stream>>>(Qb, Kb, KTg, V, aet, iw1, ib1, iw2, ib2,
                                    hkb, hqs, hkT, dvpb, w2Tb, out, bar);
}

// Round 6
// 1596.853 us; speedup vs baseline: 4.4486x; 1.1293x over previous
//
#include <hip/hip_runtime.h>
#include <hip/hip_bf16.h>

#define BB 4
#define SS 4096
#define DD 512
#define LWW 512
#define CC 64
#define NCH 64

typedef unsigned short u16;
using fragAB = __attribute__((ext_vector_type(8))) short;
using fragC  = __attribute__((ext_vector_type(4))) float;
using u16x4  = __attribute__((ext_vector_type(4))) short;

__device__ __forceinline__ short f2bf(float f){
  unsigned u = __float_as_uint(f);
  u = (u + 0x7FFFu + ((u >> 16) & 1u)) >> 16;
  return (short)u;
}
__device__ __forceinline__ float bf2f(short s){
  return __uint_as_float(((unsigned)(u16)s) << 16);
}
__device__ __forceinline__ fragC zeroC(){ fragC z = {0.f,0.f,0.f,0.f}; return z; }

__device__ __forceinline__ fragAB frag_bf16g(const u16* __restrict__ base, int ld, int r0, int k0, int lane){
  return *(const fragAB*)(base + (size_t)(r0 + (lane & 15)) * ld + k0 + ((lane >> 4) << 3));
}
__device__ __forceinline__ fragAB frag_lds(const short* base, int ld, int r0, int k0, int lane){
  return *(const fragAB*)(base + (r0 + (lane & 15)) * ld + k0 + ((lane >> 4) << 3));
}
#define MFMA16(a,b,c) __builtin_amdgcn_mfma_f32_16x16x32_bf16(a,b,c,0,0,0)

// ---- system-coherent (Infinity-Cache) access: bypass L1+L2 both sides ----
__device__ __forceinline__ void ld_sys(fragAB& r, const u16* p){
  asm volatile("global_load_dwordx4 %0, %1, off sc0 sc1" : "=v"(r) : "v"(p) : "memory");
}
__device__ __forceinline__ void st_sys2(u16* p, short v){
  asm volatile("global_store_short %0, %1, off sc0 sc1" :: "v"(p), "v"((unsigned)(u16)v) : "memory");
}
__device__ __forceinline__ void st_sys8(u16* p, u16x4 v){
  asm volatile("global_store_dwordx2 %0, %1, off sc0 sc1" :: "v"(p), "v"(v) : "memory");
}
#define WAITVM(N) do { asm volatile("s_waitcnt vmcnt(" #N ")" ::: "memory"); \
                       __builtin_amdgcn_sched_barrier(0); } while (0)

// tiled exchange layout [k/16][64 c][16]
__device__ __forceinline__ const u16* taddr(const u16* base, int c, int kq){
  return base + (((size_t)((kq >> 4)*64 + c)) << 4) + (kq & 15);
}
__device__ __forceinline__ u16* taddrw(u16* base, int c, int kq){
  return base + (((size_t)((kq >> 4)*64 + c)) << 4) + (kq & 15);
}

// ---------------- distributed per-block barrier (relaxed, no cache fences) ----------------
// slots: 32 slots per batch, 32 u32 (128 B) apart; block tl writes slot tl, wave 0 polls all 32.
__device__ __forceinline__ void bar_sync(unsigned* slots, unsigned phase, int tl){
  asm volatile("s_waitcnt vmcnt(0)" ::: "memory");
  __builtin_amdgcn_sched_barrier(0);
  __syncthreads();
  if (threadIdx.x == 0)
    __hip_atomic_store(slots + (size_t)tl*32, phase, __ATOMIC_RELAXED, __HIP_MEMORY_SCOPE_AGENT);
  if (threadIdx.x < 64){
    bool mine = threadIdx.x < 32;
    unsigned* sp = slots + (size_t)(threadIdx.x & 31)*32;
    for (;;){
      unsigned v = mine ? __hip_atomic_load(sp, __ATOMIC_RELAXED, __HIP_MEMORY_SCOPE_AGENT) : phase;
      if (__all((int)(v >= phase))) break;
      __builtin_amdgcn_s_sleep(1);
    }
  }
  __syncthreads();
}

// ---------------- fp32 -> bf16 conversions + bar zero ----------------
__global__ __launch_bounds__(256) void k_cvt(const float* __restrict__ x,
    const float* __restrict__ Wq, const float* __restrict__ Wk, const float* __restrict__ Wv,
    u16* __restrict__ xb, u16* __restrict__ Wc, unsigned* __restrict__ bar){
  size_t i = (size_t)blockIdx.x * 256 + threadIdx.x;
  if (blockIdx.x == 0){
    for (int z = threadIdx.x; z < 4096; z += 256) bar[z] = 0u;
  }
  const size_t NX4 = (size_t)BB*SS*DD/4;
  const size_t NW4 = (size_t)DD*DD/4;
  if (i < NX4){
    float4 v = ((const float4*)x)[i];
    u16x4 o = { f2bf(v.x), f2bf(v.y), f2bf(v.z), f2bf(v.w) };
    *(u16x4*)(xb + 4*i) = o;
  } else if (i < NX4 + 3*NW4){
    size_t j = i - NX4;
    const float* src = (j < NW4) ? Wq : (j < 2*NW4) ? Wk : Wv;
    size_t jj = j % NW4;
    float4 v = ((const float4*)src)[jj];
    u16x4 o = { f2bf(v.x), f2bf(v.y), f2bf(v.z), f2bf(v.w) };
    *(u16x4*)(Wc + 4*j) = o;
  }
}

// ---------------- Q,K,V projections ----------------
__global__ __launch_bounds__(256) void k_proj(const u16* __restrict__ xb,
    const u16* __restrict__ Wc,
    u16* __restrict__ Qb, u16* __restrict__ Kb, float* __restrict__ V){
  int mt = blockIdx.x / 12, nt = blockIdx.x % 12;
  int lane = threadIdx.x & 63, wid = threadIdx.x >> 6;
  int m0 = mt * 64 + wid * 16;
  const u16* Bp = Wc + (size_t)nt * 128 * DD;
  fragC acc[8];
#pragma unroll
  for (int i = 0; i < 8; ++i) acc[i] = zeroC();
  for (int k0 = 0; k0 < DD; k0 += 32){
    fragAB a = frag_bf16g(xb, DD, m0, k0, lane);
#pragma unroll
    for (int nf = 0; nf < 8; ++nf)
      acc[nf] = MFMA16(a, frag_bf16g(Bp, DD, nf*16, k0, lane), acc[nf]);
  }
#pragma unroll
  for (int nf = 0; nf < 8; ++nf){
#pragma unroll
    for (int r = 0; r < 4; ++r){
      int m = m0 + ((lane >> 4) << 2) + r;
      int col = nt*128 + nf*16 + (lane & 15);
      float v = acc[nf][r];
      if (nt < 4)      Qb[(size_t)m*DD + col]        = (u16)f2bf(v);
      else if (nt < 8) Kb[(size_t)m*DD + col - 512]  = (u16)f2bf(v);
      else             V [(size_t)m*DD + col - 1024] = v;
    }
  }
}

// ---------------- l2-normalize Q,K rows ----------------
__global__ __launch_bounds__(256) void k_norm(u16* __restrict__ Qb, u16* __restrict__ Kb){
  int idx = blockIdx.x * 4 + (threadIdx.x >> 6);
  int lane = threadIdx.x & 63;
  u16* p = (idx < BB*SS ? Qb + (size_t)idx * DD
                        : Kb + (size_t)(idx - BB*SS) * DD) + lane * 8;
  fragAB v = *(const fragAB*)p;
  float f[8]; float s = 0.f;
#pragma unroll
  for (int i = 0; i < 8; ++i){ f[i] = bf2f(v[i]); s += f[i]*f[i]; }
#pragma unroll
  for (int o = 32; o > 0; o >>= 1) s += __shfl_xor(s, o, 64);
  float inv = 1.f / fmaxf(sqrtf(s), 1e-12f);
  fragAB o8;
#pragma unroll
  for (int i = 0; i < 8; ++i) o8[i] = f2bf(f[i] * inv);
  *(fragAB*)p = o8;
}

// ---------------- transpose K ----------------
__global__ __launch_bounds__(256) void k_trans(const u16* __restrict__ Kb, u16* __restrict__ KT){
  __shared__ short tile[64][68];
  int blk = blockIdx.x;
  int b = blk >> 9, rem = blk & 511;
  int st = rem >> 3, dt = rem & 7;
  int s0 = st*64, d0 = dt*64;
  int sr = threadIdx.x & 63, q = threadIdx.x >> 6;
  const u16* src = Kb + ((size_t)b*SS + s0 + sr)*DD + d0 + q*16;
  fragAB v0 = *(const fragAB*)src;
  fragAB v1 = *(const fragAB*)(src + 8);
#pragma unroll
  for (int i = 0; i < 8; ++i){ tile[sr][q*16+i] = v0[i]; tile[sr][q*16+8+i] = v1[i]; }
  __syncthreads();
  fragAB o0, o1;
#pragma unroll
  for (int i = 0; i < 8; ++i){ o0[i] = tile[q*16+i][sr]; o1[i] = tile[q*16+8+i][sr]; }
  u16* dst = KT + ((size_t)b*DD + d0 + sr)*SS + s0 + q*16;
  *(fragAB*)dst = o0;
  *(fragAB*)(dst + 8) = o1;
}

// ---------------- gates ----------------
__global__ __launch_bounds__(256) void k_gates(const float* __restrict__ x,
    const float* __restrict__ aw, const float* __restrict__ ab,
    const float* __restrict__ ew, const float* __restrict__ eb,
    const float* __restrict__ tw, const float* __restrict__ tb,
    float* __restrict__ aet){
  __shared__ float part[64][4][3];
  __shared__ float rowsig[64][3];
  int b = blockIdx.x >> 6, t = blockIdx.x & 63;
  int tid = threadIdx.x;
  int r = tid >> 2, p = tid & 3;
  const float4* xp = (const float4*)(x + ((size_t)b*SS + (size_t)t*CC + r) * DD + p * 128);
  const float4* a4 = (const float4*)(aw + p*128);
  const float4* e4 = (const float4*)(ew + p*128);
  const float4* t4 = (const float4*)(tw + p*128);
  float s0 = 0.f, s1 = 0.f, s2 = 0.f;
  for (int i = 0; i < 32; ++i){
    float4 xv = xp[i], av = a4[i], ev = e4[i], tv = t4[i];
    s0 += xv.x*av.x + xv.y*av.y + xv.z*av.z + xv.w*av.w;
    s1 += xv.x*ev.x + xv.y*ev.y + xv.z*ev.z + xv.w*ev.w;
    s2 += xv.x*tv.x + xv.y*tv.y + xv.z*tv.z + xv.w*tv.w;
  }
  part[r][p][0] = s0; part[r][p][1] = s1; part[r][p][2] = s2;
  __syncthreads();
  if (tid < 64){
    float a_ = part[tid][0][0]+part[tid][1][0]+part[tid][2][0]+part[tid][3][0] + ab[0];
    float e_ = part[tid][0][1]+part[tid][1][1]+part[tid][2][1]+part[tid][3][1] + eb[0];
    float t_ = part[tid][0][2]+part[tid][1][2]+part[tid][2][2]+part[tid][3][2] + tb[0];
    rowsig[tid][0] = 1.f/(1.f+expf(-a_));
    rowsig[tid][1] = 1.f/(1.f+expf(-e_));
    rowsig[tid][2] = 1.f/(1.f+expf(-t_));
  }
  __syncthreads();
  if (tid < 3){
    float s = 0.f;
    for (int i = 0; i < 64; ++i) s += rowsig[i][tid];
    aet[((size_t)b*NCH + t)*3 + tid] = s * (1.f/64.f);
  }
}

// ---------------- persistent fused scan (R4 protocol + LDS dh-prefetch + distributed barrier) ----------------
__global__ __launch_bounds__(512, 2) void k_scan(
    const u16* __restrict__ Qb, const u16* __restrict__ Kb, const u16* __restrict__ KTg,
    const float* __restrict__ V, const float* __restrict__ aet,
    const float* __restrict__ iw1, const float* __restrict__ ib1,
    const float* __restrict__ iw2, const float* __restrict__ ib2,
    u16* __restrict__ hkb, u16* __restrict__ hqs, u16* __restrict__ hkT,
    u16* __restrict__ dvpb, u16* __restrict__ w2Tb,
    float* __restrict__ out, unsigned* __restrict__ barb)
{
  __shared__ __align__(16) short s_w1[16*520];
  __shared__ __align__(16) short s_w2[16*520];
  __shared__ __align__(16) short s_pf[16*520];   // prefetched w2T tile for next dh
  __shared__ __align__(16) short s_t[16*72];
  __shared__ float s_b1[16], s_mb1[16], s_b2[16], s_mb2[16];

  const int tid  = threadIdx.x;
  const int lane = tid & 63;
  const int wid  = tid >> 6;
  const int q    = lane >> 4;
  const int l15  = lane & 15;
  const int qk   = q << 3;
  const int b    = (blockIdx.x & 7) >> 1;
  const int tl   = ((blockIdx.x >> 3) << 1) | (blockIdx.x & 1);
  const int h0   = tl * 16;
  const int d0   = tl * 16;
  unsigned* slots = barb + (size_t)b * 1024;
  unsigned  ph   = 0;

  const u16* Kball = Kb  + (size_t)b*SS*DD;
  const u16* Qball = Qb  + (size_t)b*SS*DD;
  const u16* KTbat = KTg + (size_t)b*DD*SS;
  u16* hk_b  = hkb  + (size_t)b*CC*LWW;
  u16* hq_b  = hqs  + (size_t)b*CC*LWW;
  u16* hkT_b = hkT  + (size_t)b*LWW*CC;
  u16* dv_b  = dvpb + (size_t)b*CC*DD;
  const size_t W2TBUF = (size_t)BB*DD*LWW;

  float w1f[16], mw1f[16], w2f[16], mw2f[16], actr[4];

  // ---- preamble: init state; initial w2T -> buf[0] ----
  {
    u16* w2T0 = w2Tb + (size_t)b*DD*LWW;
#pragma unroll
    for (int nf = 0; nf < 4; ++nf){
      u16x4 pk;
#pragma unroll
      for (int r = 0; r < 4; ++r){
        int hr = q*4 + r;
        int dcol = wid*64 + nf*16 + l15;
        float a = iw1[(size_t)(h0 + hr)*DD + dcol];
        w1f[nf*4+r] = a; mw1f[nf*4+r] = 0.f;
        s_w1[hr*520 + dcol] = f2bf(a);
        float c = iw2[(size_t)(d0 + hr)*LWW + dcol];
        w2f[nf*4+r] = c; mw2f[nf*4+r] = 0.f;
        s_w2[hr*520 + dcol] = f2bf(c);
        pk[r] = f2bf(c);
      }
      st_sys8(w2T0 + (size_t)(wid*64 + nf*16 + l15)*DD + d0 + q*4, pk);
    }
    if (tid < 16){
      s_b1[tid] = ib1[h0 + tid]; s_mb1[tid] = 0.f;
      s_b2[tid] = ib2[d0 + tid]; s_mb2[tid] = 0.f;
    }
#pragma unroll
    for (int r = 0; r < 4; ++r) actr[r] = 0.f;
    WAITVM(0);
    __syncthreads();
  }

  for (int t = 0; t < NCH; ++t){
    // ======== PHASE A ========
    if (t > 0){
      // g_w1 B-fragments: cached loads of KT chunk t-1 (issued first; drained by WAITVM(0) below)
      fragAB kfr[8];
      {
        const u16* KTm = KTbat + (size_t)(t-1)*CC;
#pragma unroll
        for (int nf = 0; nf < 4; ++nf)
#pragma unroll
          for (int kk = 0; kk < 2; ++kk)
            kfr[nf*2+kk] = frag_bf16g(KTm, SS, wid*64 + nf*16, kk*32, lane);
      }
      // dh (waves 0-3): A = dvp sys loads (newest-8 counted), B = s_pf (prefetched w2T tile)
      if (wid < 4){
        fragAB fa[8];
        fragC a0 = zeroC();
#pragma unroll
        for (int j = 0; j < 8; ++j) ld_sys(fa[j], taddr(dv_b, wid*16 + l15, j*32 + qk));
        WAITVM(4);
#pragma unroll
        for (int j = 0; j < 4; ++j) a0 = MFMA16(fa[j], frag_lds(s_pf, 520, 0, j*32, lane), a0);
#pragma unroll
        for (int j = 0; j < 4; ++j) ld_sys(fa[j], taddr(dv_b, wid*16 + l15, (8+j)*32 + qk));
        WAITVM(4);
#pragma unroll
        for (int j = 0; j < 4; ++j) a0 = MFMA16(fa[4+j], frag_lds(s_pf, 520, 0, 128 + j*32, lane), a0);
#pragma unroll
        for (int j = 0; j < 4; ++j) ld_sys(fa[4+j], taddr(dv_b, wid*16 + l15, (12+j)*32 + qk));
        WAITVM(4);
#pragma unroll
        for (int j = 0; j < 4; ++j) a0 = MFMA16(fa[j], frag_lds(s_pf, 520, 0, 256 + j*32, lane), a0);
        WAITVM(0);
#pragma unroll
        for (int j = 0; j < 4; ++j) a0 = MFMA16(fa[4+j], frag_lds(s_pf, 520, 0, 384 + j*32, lane), a0);
#pragma unroll
        for (int r = 0; r < 4; ++r)
          s_t[l15*72 + wid*16 + q*4 + r] = f2bf(a0[r] * actr[r]);
      }
      __syncthreads();
      WAITVM(0);   // ensure kfr landed (waves 4-7)
      { // g_w1 [16 h][512 d], K = 64 c
        fragC ag[4];
#pragma unroll
        for (int i = 0; i < 4; ++i) ag[i] = zeroC();
#pragma unroll
        for (int kk = 0; kk < 2; ++kk){
          fragAB af = frag_lds(s_t, 72, 0, kk*32, lane);
#pragma unroll
          for (int nf = 0; nf < 4; ++nf)
            ag[nf] = MFMA16(af, kfr[nf*2+kk], ag[nf]);
        }
        const float* g3 = aet + ((size_t)b*NCH + (t-1)) * 3;
        float ga = g3[0], ge = g3[1], gth = g3[2];
#pragma unroll
        for (int nf = 0; nf < 4; ++nf)
#pragma unroll
          for (int r = 0; r < 4; ++r){
            float g  = ag[nf][r] * (1.f/64.f);
            float m_ = ge*mw1f[nf*4+r] - gth*g;
            float w_ = (1.f-ga)*w1f[nf*4+r] + m_;
            mw1f[nf*4+r] = m_; w1f[nf*4+r] = w_;
            s_w1[(q*4+r)*520 + wid*64 + nf*16 + l15] = f2bf(w_);
          }
        if (tid < 16){
          const fragAB* row = (const fragAB*)(s_t + tid*72);
          float s = 0.f;
#pragma unroll
          for (int j = 0; j < 8; ++j){
            fragAB v = row[j];
#pragma unroll
            for (int i = 0; i < 8; ++i) s += bf2f(v[i]);
          }
          float gb = s * (1.f/64.f);
          float m_ = ge*s_mb1[tid] - gth*gb;
          float bn = (1.f-ga)*s_b1[tid] + m_;
          s_mb1[tid] = m_; s_b1[tid] = bn;
        }
      }
    }
    __syncthreads();
    // pre (waves 0-3, K) & hq (waves 4-7, Q), cached A + LDS B
    {
      const u16* Ac = (wid < 4 ? Kball : Qball) + (size_t)t*CC*DD;
      int m0 = (wid & 3) * 16;
      fragC acc = zeroC();
      for (int k0 = 0; k0 < DD; k0 += 32)
        acc = MFMA16(frag_bf16g(Ac, DD, m0, k0, lane),
                     frag_lds(s_w1, 520, 0, k0, lane), acc);
      float bb = s_b1[l15];
      if (wid < 4){
        u16x4 pk;
#pragma unroll
        for (int r = 0; r < 4; ++r){
          int c = m0 + q*4 + r;
          float pre = acc[r] + bb;
          float sg  = 1.f/(1.f+expf(-pre));
          float hkv = pre * sg;
          actr[r]   = sg * (1.f + pre * (1.f - sg));
          short hb  = f2bf(hkv);
          st_sys2(taddrw(hk_b, c, h0 + l15), hb);
          pk[r] = hb;
        }
        st_sys8(hkT_b + (size_t)(h0 + l15)*CC + m0 + q*4, pk);
      } else {
#pragma unroll
        for (int r = 0; r < 4; ++r){
          int c = m0 + q*4 + r;
          float hqv = acc[r] + bb;
          float s2  = 1.f/(1.f+expf(-hqv));
          st_sys2(taddrw(hq_b, c, h0 + l15), f2bf(hqv * s2));
        }
      }
    }
    ph++; bar_sync(slots, ph, tl);

    // ======== PHASE B ========
    {
      const u16* Ah = (wid < 4) ? hq_b : hk_b;
      int m0 = (wid & 3) * 16;
      fragC acc = zeroC();
      fragAB va[4], vb[4], hfr[8];
      float vv[4];
      if (wid >= 4){
#pragma unroll
        for (int r = 0; r < 4; ++r)
          vv[r] = V[((size_t)b*SS + (size_t)t*CC + m0 + q*4 + r)*DD + d0 + l15];
      }
#pragma unroll
      for (int j = 0; j < 4; ++j) ld_sys(va[j], taddr(Ah, m0 + l15, j*32 + qk));
#pragma unroll
      for (int j = 0; j < 4; ++j) ld_sys(vb[j], taddr(Ah, m0 + l15, 128 + j*32 + qk));
      WAITVM(4);
#pragma unroll
      for (int j = 0; j < 4; ++j) acc = MFMA16(va[j], frag_lds(s_w2, 520, 0, j*32, lane), acc);
#pragma unroll
      for (int j = 0; j < 4; ++j) ld_sys(va[j], taddr(Ah, m0 + l15, 256 + j*32 + qk));
      WAITVM(4);
#pragma unroll
      for (int j = 0; j < 4; ++j) acc = MFMA16(vb[j], frag_lds(s_w2, 520, 0, 128 + j*32, lane), acc);
#pragma unroll
      for (int j = 0; j < 4; ++j) ld_sys(vb[j], taddr(Ah, m0 + l15, 384 + j*32 + qk));
      WAITVM(4);
#pragma unroll
      for (int j = 0; j < 4; ++j) acc = MFMA16(va[j], frag_lds(s_w2, 520, 0, 256 + j*32, lane), acc);
#pragma unroll
      for (int nf = 0; nf < 4; ++nf)
#pragma unroll
        for (int kk = 0; kk < 2; ++kk)
          ld_sys(hfr[nf*2+kk], hkT_b + (size_t)(wid*64 + nf*16 + l15)*CC + kk*32 + qk);
      WAITVM(8);
#pragma unroll
      for (int j = 0; j < 4; ++j) acc = MFMA16(vb[j], frag_lds(s_w2, 520, 0, 384 + j*32, lane), acc);

      float bb = s_b2[l15];
      if (wid < 4){
#pragma unroll
        for (int r = 0; r < 4; ++r){
          int c = m0 + q*4 + r;
          __builtin_nontemporal_store(acc[r] + bb,
            &out[((size_t)b*SS + (size_t)t*CC + c)*DD + d0 + l15]);
        }
      } else {
#pragma unroll
        for (int r = 0; r < 4; ++r){
          int c = m0 + q*4 + r;
          float dvv = (acc[r] + bb - vv[r]) * (2.f/512.f);
          short db_ = f2bf(dvv);
          st_sys2(taddrw(dv_b, c, d0 + l15), db_);
          s_t[l15*72 + c] = db_;
        }
      }
      __syncthreads();
      WAITVM(0);
      // g_w2 [16 d][512 h], K = 64 c; updates; w2T stores; b2; s_pf prefetch for dh(t+1)
      {
        fragC ag[4];
#pragma unroll
        for (int i = 0; i < 4; ++i) ag[i] = zeroC();
#pragma unroll
        for (int kk = 0; kk < 2; ++kk){
          fragAB af = frag_lds(s_t, 72, 0, kk*32, lane);
#pragma unroll
          for (int nf = 0; nf < 4; ++nf)
            ag[nf] = MFMA16(af, hfr[nf*2+kk], ag[nf]);
        }
        const float* g3 = aet + ((size_t)b*NCH + t) * 3;
        float ga = g3[0], ge = g3[1], gth = g3[2];
        u16* w2Tn = w2Tb + (size_t)((t+1)&1)*W2TBUF + (size_t)b*DD*LWW;
#pragma unroll
        for (int nf = 0; nf < 4; ++nf){
          u16x4 pk;
#pragma unroll
          for (int r = 0; r < 4; ++r){
            float g  = ag[nf][r] * (1.f/64.f);
            float m_ = ge*mw2f[nf*4+r] - gth*g;
            float w_ = (1.f-ga)*w2f[nf*4+r] + m_;
            mw2f[nf*4+r] = m_; w2f[nf*4+r] = w_;
            short wb = f2bf(w_);
            s_w2[(q*4+r)*520 + wid*64 + nf*16 + l15] = wb;
            pk[r] = wb;
          }
          st_sys8(w2Tn + (size_t)(wid*64 + nf*16 + l15)*DD + d0 + q*4, pk);
        }
        if (tid < 16){
          const fragAB* row = (const fragAB*)(s_t + tid*72);
          float s = 0.f;
#pragma unroll
          for (int j = 0; j < 8; ++j){
            fragAB v = row[j];
#pragma unroll
            for (int i = 0; i < 8; ++i) s += bf2f(v[i]);
          }
          float gb = s * (1.f/64.f);
          float m_ = ge*s_mb2[tid] - gth*gb;
          float bn = (1.f-ga)*s_b2[tid] + m_;
          s_mb2[tid] = m_; s_b2[tid] = bn;
        }
        if (t + 1 < NCH){
          // cooperative prefetch: s_pf[hr][c0..c0+15] = w2T(buf[t&1])[h0+hr][c0..]
          const u16* w2Tp = w2Tb + (size_t)(t&1)*W2TBUF + (size_t)b*DD*LWW;
          int hr = tid >> 5;
          int c0 = (tid & 31) << 4;
          const u16* src = w2Tp + (size_t)(h0 + hr)*DD + c0;
          fragAB t0, t1;
          ld_sys(t0, src);
          ld_sys(t1, src + 8);
          WAITVM(0);
          *(fragAB*)(s_pf + hr*520 + c0)     = t0;
          *(fragAB*)(s_pf + hr*520 + c0 + 8) = t1;
        }
      }
    }
    ph++; bar_sync(slots, ph, tl);
  }
}

extern "C" void kernel_launch(void* const* d_in, const int* in_sizes, int n_in,
                              void* d_out, int out_size, void* d_ws, size_t ws_size,
                              hipStream_t stream){
  const float* x   = (const float*)d_in[0];
  const float* Wq  = (const float*)d_in[1];
  const float* Wk  = (const float*)d_in[2];
  const float* Wv  = (const float*)d_in[3];
  const float* iw1 = (const float*)d_in[4];
  const float* ib1 = (const float*)d_in[5];
  const float* iw2 = (const float*)d_in[6];
  const float* ib2 = (const float*)d_in[7];
  const float* aw  = (const float*)d_in[8];
  const float* ab  = (const float*)d_in[9];
  const float* ew  = (const float*)d_in[10];
  const float* eb  = (const float*)d_in[11];
  const float* tw  = (const float*)d_in[12];
  const float* tb  = (const float*)d_in[13];
  float* out = (float*)d_out;

  float* fw = (float*)d_ws;
  float* V    = fw;  fw += (size_t)BB*SS*DD;
  float* aet  = fw;  fw += (size_t)BB*NCH*3 + 64;
  unsigned* bar = (unsigned*)fw; fw += 4096;
  u16* xb   = (u16*)fw;                       // aliased as KTg after k_proj
  u16* Wc   = xb   + (size_t)BB*SS*DD;
  u16* Qb   = Wc   + (size_t)3*DD*DD;
  u16* Kb   = Qb   + (size_t)BB*SS*DD;
  u16* hkb  = Kb   + (size_t)BB*SS*DD;
  u16* hqs  = hkb  + (size_t)BB*CC*LWW;
  u16* hkT  = hqs  + (size_t)BB*CC*LWW;
  u16* dvpb = hkT  + (size_t)BB*LWW*CC;
  u16* w2Tb = dvpb + (size_t)BB*CC*DD;        // 2 buffers of BB*DD*LWW
  u16* KTg  = xb;

  k_cvt  <<<8960, 256, 0, stream>>>(x, Wq, Wk, Wv, xb, Wc, bar);
  k_proj <<<3072, 256, 0, stream>>>(xb, Wc, Qb, Kb, V);
  k_norm <<<8192, 256, 0, stream>>>(Qb, Kb);
  k_trans<<<2048, 256, 0, stream>>>(Kb, KTg);
  k_gates<<<256,  256, 0, stream>>>(x, aw, ab, ew, eb, tw, tb, aet);
  k_scan <<<128,  512, 0, stream>>>(Qb, Kb, KTg, V, aet, iw1, ib1, iw2, ib2,
                                    hkb, hqs, hkT, dvpb, w2Tb, out, bar);
}

// Round 7
// 1437.922 us; speedup vs baseline: 4.9403x; 1.1105x over previous
//
#include <hip/hip_runtime.h>
#include <hip/hip_bf16.h>

#define BB 4
#define SS 4096
#define DD 512
#define LWW 512
#define CC 64
#define NCH 64

typedef unsigned short u16;
using fragAB = __attribute__((ext_vector_type(8))) short;
using fragC  = __attribute__((ext_vector_type(4))) float;
using u16x4  = __attribute__((ext_vector_type(4))) short;

__device__ __forceinline__ short f2bf(float f){
  unsigned u = __float_as_uint(f);
  u = (u + 0x7FFFu + ((u >> 16) & 1u)) >> 16;
  return (short)u;
}
__device__ __forceinline__ float bf2f(short s){
  return __uint_as_float(((unsigned)(u16)s) << 16);
}
__device__ __forceinline__ fragC zeroC(){ fragC z = {0.f,0.f,0.f,0.f}; return z; }

__device__ __forceinline__ fragAB frag_bf16g(const u16* __restrict__ base, int ld, int r0, int k0, int lane){
  return *(const fragAB*)(base + (size_t)(r0 + (lane & 15)) * ld + k0 + ((lane >> 4) << 3));
}
__device__ __forceinline__ fragAB frag_lds(const short* base, int ld, int r0, int k0, int lane){
  return *(const fragAB*)(base + (r0 + (lane & 15)) * ld + k0 + ((lane >> 4) << 3));
}
#define MFMA16(a,b,c) __builtin_amdgcn_mfma_f32_16x16x32_bf16(a,b,c,0,0,0)

// ---- system-coherent (Infinity-Cache) access ----
__device__ __forceinline__ void ld_sys(fragAB& r, const u16* p){
  asm volatile("global_load_dwordx4 %0, %1, off sc0 sc1" : "=v"(r) : "v"(p) : "memory");
}
__device__ __forceinline__ void st_sys8(u16* p, u16x4 v){
  asm volatile("global_store_dwordx2 %0, %1, off sc0 sc1" :: "v"(p), "v"(v) : "memory");
}
__device__ __forceinline__ void st_sys16(u16* p, fragAB v){
  asm volatile("global_store_dwordx4 %0, %1, off sc0 sc1" :: "v"(p), "v"(v) : "memory");
}
#define WAITVM(N) do { asm volatile("s_waitcnt vmcnt(" #N ")" ::: "memory"); \
                       __builtin_amdgcn_sched_barrier(0); } while (0)

// tiled exchange layout [k/16][64 c][16]
__device__ __forceinline__ const u16* taddr(const u16* base, int c, int kq){
  return base + (((size_t)((kq >> 4)*64 + c)) << 4) + (kq & 15);
}

// ---------------- distributed per-batch barrier ----------------
__device__ __forceinline__ void bar_sync(unsigned* slots, unsigned phase, int tl){
  asm volatile("s_waitcnt vmcnt(0)" ::: "memory");
  __builtin_amdgcn_sched_barrier(0);
  __syncthreads();
  if (threadIdx.x == 0)
    __hip_atomic_store(slots + (size_t)tl*32, phase, __ATOMIC_RELAXED, __HIP_MEMORY_SCOPE_AGENT);
  if (threadIdx.x < 64){
    bool mine = threadIdx.x < 32;
    unsigned* sp = slots + (size_t)(threadIdx.x & 31)*32;
    for (;;){
      unsigned v = mine ? __hip_atomic_load(sp, __ATOMIC_RELAXED, __HIP_MEMORY_SCOPE_AGENT) : phase;
      if (__all((int)(v >= phase))) break;
      __builtin_amdgcn_s_sleep(1);
    }
  }
  __syncthreads();
}

// ---------------- fp32 -> bf16 conversions + bar zero ----------------
__global__ __launch_bounds__(256) void k_cvt(const float* __restrict__ x,
    const float* __restrict__ Wq, const float* __restrict__ Wk, const float* __restrict__ Wv,
    u16* __restrict__ xb, u16* __restrict__ Wc, unsigned* __restrict__ bar){
  size_t i = (size_t)blockIdx.x * 256 + threadIdx.x;
  if (blockIdx.x == 0){
    for (int z = threadIdx.x; z < 4096; z += 256) bar[z] = 0u;
  }
  const size_t NX4 = (size_t)BB*SS*DD/4;
  const size_t NW4 = (size_t)DD*DD/4;
  if (i < NX4){
    float4 v = ((const float4*)x)[i];
    u16x4 o = { f2bf(v.x), f2bf(v.y), f2bf(v.z), f2bf(v.w) };
    *(u16x4*)(xb + 4*i) = o;
  } else if (i < NX4 + 3*NW4){
    size_t j = i - NX4;
    const float* src = (j < NW4) ? Wq : (j < 2*NW4) ? Wk : Wv;
    size_t jj = j % NW4;
    float4 v = ((const float4*)src)[jj];
    u16x4 o = { f2bf(v.x), f2bf(v.y), f2bf(v.z), f2bf(v.w) };
    *(u16x4*)(Wc + 4*j) = o;
  }
}

// ---------------- Q,K,V projections ----------------
__global__ __launch_bounds__(256) void k_proj(const u16* __restrict__ xb,
    const u16* __restrict__ Wc,
    u16* __restrict__ Qb, u16* __restrict__ Kb, float* __restrict__ V){
  int mt = blockIdx.x / 12, nt = blockIdx.x % 12;
  int lane = threadIdx.x & 63, wid = threadIdx.x >> 6;
  int m0 = mt * 64 + wid * 16;
  const u16* Bp = Wc + (size_t)nt * 128 * DD;
  fragC acc[8];
#pragma unroll
  for (int i = 0; i < 8; ++i) acc[i] = zeroC();
  for (int k0 = 0; k0 < DD; k0 += 32){
    fragAB a = frag_bf16g(xb, DD, m0, k0, lane);
#pragma unroll
    for (int nf = 0; nf < 8; ++nf)
      acc[nf] = MFMA16(a, frag_bf16g(Bp, DD, nf*16, k0, lane), acc[nf]);
  }
#pragma unroll
  for (int nf = 0; nf < 8; ++nf){
#pragma unroll
    for (int r = 0; r < 4; ++r){
      int m = m0 + ((lane >> 4) << 2) + r;
      int col = nt*128 + nf*16 + (lane & 15);
      float v = acc[nf][r];
      if (nt < 4)      Qb[(size_t)m*DD + col]        = (u16)f2bf(v);
      else if (nt < 8) Kb[(size_t)m*DD + col - 512]  = (u16)f2bf(v);
      else             V [(size_t)m*DD + col - 1024] = v;
    }
  }
}

// ---------------- l2-normalize Q,K rows ----------------
__global__ __launch_bounds__(256) void k_norm(u16* __restrict__ Qb, u16* __restrict__ Kb){
  int idx = blockIdx.x * 4 + (threadIdx.x >> 6);
  int lane = threadIdx.x & 63;
  u16* p = (idx < BB*SS ? Qb + (size_t)idx * DD
                        : Kb + (size_t)(idx - BB*SS) * DD) + lane * 8;
  fragAB v = *(const fragAB*)p;
  float f[8]; float s = 0.f;
#pragma unroll
  for (int i = 0; i < 8; ++i){ f[i] = bf2f(v[i]); s += f[i]*f[i]; }
#pragma unroll
  for (int o = 32; o > 0; o >>= 1) s += __shfl_xor(s, o, 64);
  float inv = 1.f / fmaxf(sqrtf(s), 1e-12f);
  fragAB o8;
#pragma unroll
  for (int i = 0; i < 8; ++i) o8[i] = f2bf(f[i] * inv);
  *(fragAB*)p = o8;
}

// ---------------- transpose K ----------------
__global__ __launch_bounds__(256) void k_trans(const u16* __restrict__ Kb, u16* __restrict__ KT){
  __shared__ short tile[64][68];
  int blk = blockIdx.x;
  int b = blk >> 9, rem = blk & 511;
  int st = rem >> 3, dt = rem & 7;
  int s0 = st*64, d0 = dt*64;
  int sr = threadIdx.x & 63, q = threadIdx.x >> 6;
  const u16* src = Kb + ((size_t)b*SS + s0 + sr)*DD + d0 + q*16;
  fragAB v0 = *(const fragAB*)src;
  fragAB v1 = *(const fragAB*)(src + 8);
#pragma unroll
  for (int i = 0; i < 8; ++i){ tile[sr][q*16+i] = v0[i]; tile[sr][q*16+8+i] = v1[i]; }
  __syncthreads();
  fragAB o0, o1;
#pragma unroll
  for (int i = 0; i < 8; ++i){ o0[i] = tile[q*16+i][sr]; o1[i] = tile[q*16+8+i][sr]; }
  u16* dst = KT + ((size_t)b*DD + d0 + sr)*SS + s0 + q*16;
  *(fragAB*)dst = o0;
  *(fragAB*)(dst + 8) = o1;
}

// ---------------- gates ----------------
__global__ __launch_bounds__(256) void k_gates(const float* __restrict__ x,
    const float* __restrict__ aw, const float* __restrict__ ab,
    const float* __restrict__ ew, const float* __restrict__ eb,
    const float* __restrict__ tw, const float* __restrict__ tb,
    float* __restrict__ aet){
  __shared__ float part[64][4][3];
  __shared__ float rowsig[64][3];
  int b = blockIdx.x >> 6, t = blockIdx.x & 63;
  int tid = threadIdx.x;
  int r = tid >> 2, p = tid & 3;
  const float4* xp = (const float4*)(x + ((size_t)b*SS + (size_t)t*CC + r) * DD + p * 128);
  const float4* a4 = (const float4*)(aw + p*128);
  const float4* e4 = (const float4*)(ew + p*128);
  const float4* t4 = (const float4*)(tw + p*128);
  float s0 = 0.f, s1 = 0.f, s2 = 0.f;
  for (int i = 0; i < 32; ++i){
    float4 xv = xp[i], av = a4[i], ev = e4[i], tv = t4[i];
    s0 += xv.x*av.x + xv.y*av.y + xv.z*av.z + xv.w*av.w;
    s1 += xv.x*ev.x + xv.y*ev.y + xv.z*ev.z + xv.w*ev.w;
    s2 += xv.x*tv.x + xv.y*tv.y + xv.z*tv.z + xv.w*tv.w;
  }
  part[r][p][0] = s0; part[r][p][1] = s1; part[r][p][2] = s2;
  __syncthreads();
  if (tid < 64){
    float a_ = part[tid][0][0]+part[tid][1][0]+part[tid][2][0]+part[tid][3][0] + ab[0];
    float e_ = part[tid][0][1]+part[tid][1][1]+part[tid][2][1]+part[tid][3][1] + eb[0];
    float t_ = part[tid][0][2]+part[tid][1][2]+part[tid][2][2]+part[tid][3][2] + tb[0];
    rowsig[tid][0] = 1.f/(1.f+expf(-a_));
    rowsig[tid][1] = 1.f/(1.f+expf(-e_));
    rowsig[tid][2] = 1.f/(1.f+expf(-t_));
  }
  __syncthreads();
  if (tid < 3){
    float s = 0.f;
    for (int i = 0; i < 64; ++i) s += rowsig[i][tid];
    aet[((size_t)b*NCH + t)*3 + tid] = s * (1.f/64.f);
  }
}

// ---------------- persistent fused scan ----------------
__global__ __launch_bounds__(512, 2) void k_scan(
    const u16* __restrict__ Qb, const u16* __restrict__ Kb, const u16* __restrict__ KTg,
    const float* __restrict__ V, const float* __restrict__ aet,
    const float* __restrict__ iw1, const float* __restrict__ ib1,
    const float* __restrict__ iw2, const float* __restrict__ ib2,
    u16* __restrict__ hkb, u16* __restrict__ hqs, u16* __restrict__ hkT,
    u16* __restrict__ dvpb, u16* __restrict__ w2Tb,
    float* __restrict__ out, unsigned* __restrict__ barb)
{
  __shared__ __align__(16) short s_w1[16*520];
  __shared__ __align__(16) short s_w2[16*520];
  __shared__ __align__(16) short s_pf[16*520];   // prefetched w2T tile for next dh
  __shared__ __align__(16) short s_t[16*72];
  __shared__ __align__(16) short s_hk[64*16];    // phase A hk staging / phase B dv staging
  __shared__ __align__(16) short s_hq[64*16];    // phase A hq staging
  __shared__ float s_part[64][17];               // dh K-split partials (waves 4-7)
  __shared__ float s_b1[16], s_mb1[16], s_b2[16], s_mb2[16];

  const int tid  = threadIdx.x;
  const int lane = tid & 63;
  const int wid  = tid >> 6;
  const int q    = lane >> 4;
  const int l15  = lane & 15;
  const int qk   = q << 3;
  const int b    = (blockIdx.x & 7) >> 1;
  const int tl   = ((blockIdx.x >> 3) << 1) | (blockIdx.x & 1);
  const int h0   = tl * 16;
  const int d0   = tl * 16;
  unsigned* slots = barb + (size_t)b * 1024;
  unsigned  ph   = 0;

  const u16* Kball = Kb  + (size_t)b*SS*DD;
  const u16* Qball = Qb  + (size_t)b*SS*DD;
  const u16* KTbat = KTg + (size_t)b*DD*SS;
  u16* hk_b  = hkb  + (size_t)b*CC*LWW;
  u16* hq_b  = hqs  + (size_t)b*CC*LWW;
  u16* hkT_b = hkT  + (size_t)b*LWW*CC;
  u16* dv_b  = dvpb + (size_t)b*CC*DD;
  const size_t W2TBUF = (size_t)BB*DD*LWW;

  float w1f[16], mw1f[16], w2f[16], mw2f[16], actr[4];

  // ---- preamble: init state; initial w2T -> buf[0] ----
  {
    u16* w2T0 = w2Tb + (size_t)b*DD*LWW;
#pragma unroll
    for (int nf = 0; nf < 4; ++nf){
      u16x4 pk;
#pragma unroll
      for (int r = 0; r < 4; ++r){
        int hr = q*4 + r;
        int dcol = wid*64 + nf*16 + l15;
        float a = iw1[(size_t)(h0 + hr)*DD + dcol];
        w1f[nf*4+r] = a; mw1f[nf*4+r] = 0.f;
        s_w1[hr*520 + dcol] = f2bf(a);
        float c = iw2[(size_t)(d0 + hr)*LWW + dcol];
        w2f[nf*4+r] = c; mw2f[nf*4+r] = 0.f;
        s_w2[hr*520 + dcol] = f2bf(c);
        pk[r] = f2bf(c);
      }
      st_sys8(w2T0 + (size_t)(wid*64 + nf*16 + l15)*DD + d0 + q*4, pk);
    }
    if (tid < 16){
      s_b1[tid] = ib1[h0 + tid]; s_mb1[tid] = 0.f;
      s_b2[tid] = ib2[d0 + tid]; s_mb2[tid] = 0.f;
    }
#pragma unroll
    for (int r = 0; r < 4; ++r) actr[r] = 0.f;
    WAITVM(0);
    __syncthreads();
  }

  for (int t = 0; t < NCH; ++t){
    // ======== PHASE A ========
    if (t > 0){
      // g_w1 B-fragments: cached KT(t-1) loads (retire before counted waits below)
      fragAB kfr[8];
      {
        const u16* KTm = KTbat + (size_t)(t-1)*CC;
#pragma unroll
        for (int nf = 0; nf < 4; ++nf)
#pragma unroll
          for (int kk = 0; kk < 2; ++kk)
            kfr[nf*2+kk] = frag_bf16g(KTm, SS, wid*64 + nf*16, kk*32, lane);
      }
      // dh K-split: all 8 waves; waves 0-3 k=0..255, waves 4-7 k=256..511
      {
        const int cst = (wid & 3) * 16;      // c-strip
        const int kh  = (wid >> 2) * 256;    // k-half base
        fragAB fa[8];
        fragC a0 = zeroC();
#pragma unroll
        for (int j = 0; j < 8; ++j) ld_sys(fa[j], taddr(dv_b, cst + l15, kh + j*32 + qk));
        WAITVM(4);
#pragma unroll
        for (int j = 0; j < 4; ++j) a0 = MFMA16(fa[j], frag_lds(s_pf, 520, 0, kh + j*32, lane), a0);
        WAITVM(0);
#pragma unroll
        for (int j = 4; j < 8; ++j) a0 = MFMA16(fa[j], frag_lds(s_pf, 520, 0, kh + j*32, lane), a0);
        if (wid >= 4){
#pragma unroll
          for (int r = 0; r < 4; ++r) s_part[cst + q*4 + r][l15] = a0[r];
        }
        __syncthreads();
        if (wid < 4){
#pragma unroll
          for (int r = 0; r < 4; ++r){
            float v = (a0[r] + s_part[cst + q*4 + r][l15]) * actr[r];
            s_t[l15*72 + cst + q*4 + r] = f2bf(v);
          }
        }
      }
      __syncthreads();
      { // g_w1 [16 h][512 d], K = 64 c
        fragC ag[4];
#pragma unroll
        for (int i = 0; i < 4; ++i) ag[i] = zeroC();
#pragma unroll
        for (int kk = 0; kk < 2; ++kk){
          fragAB af = frag_lds(s_t, 72, 0, kk*32, lane);
#pragma unroll
          for (int nf = 0; nf < 4; ++nf)
            ag[nf] = MFMA16(af, kfr[nf*2+kk], ag[nf]);
        }
        const float* g3 = aet + ((size_t)b*NCH + (t-1)) * 3;
        float ga = g3[0], ge = g3[1], gth = g3[2];
#pragma unroll
        for (int nf = 0; nf < 4; ++nf)
#pragma unroll
          for (int r = 0; r < 4; ++r){
            float g  = ag[nf][r] * (1.f/64.f);
            float m_ = ge*mw1f[nf*4+r] - gth*g;
            float w_ = (1.f-ga)*w1f[nf*4+r] + m_;
            mw1f[nf*4+r] = m_; w1f[nf*4+r] = w_;
            s_w1[(q*4+r)*520 + wid*64 + nf*16 + l15] = f2bf(w_);
          }
        if (tid < 16){
          const fragAB* row = (const fragAB*)(s_t + tid*72);
          float s = 0.f;
#pragma unroll
          for (int j = 0; j < 8; ++j){
            fragAB v = row[j];
#pragma unroll
            for (int i = 0; i < 8; ++i) s += bf2f(v[i]);
          }
          float gb = s * (1.f/64.f);
          float m_ = ge*s_mb1[tid] - gth*gb;
          float bn = (1.f-ga)*s_b1[tid] + m_;
          s_mb1[tid] = m_; s_b1[tid] = bn;
        }
      }
    }
    __syncthreads();
    // pre (waves 0-3, K) & hq (waves 4-7, Q): cached A + LDS B; stage results to LDS
    {
      const u16* Ac = (wid < 4 ? Kball : Qball) + (size_t)t*CC*DD;
      int m0 = (wid & 3) * 16;
      fragC acc = zeroC();
      for (int k0 = 0; k0 < DD; k0 += 32)
        acc = MFMA16(frag_bf16g(Ac, DD, m0, k0, lane),
                     frag_lds(s_w1, 520, 0, k0, lane), acc);
      float bb = s_b1[l15];
      if (wid < 4){
        u16x4 pk;
#pragma unroll
        for (int r = 0; r < 4; ++r){
          int c = m0 + q*4 + r;
          float pre = acc[r] + bb;
          float sg  = 1.f/(1.f+expf(-pre));
          float hkv = pre * sg;
          actr[r]   = sg * (1.f + pre * (1.f - sg));
          short hb  = f2bf(hkv);
          s_hk[c*16 + l15] = hb;
          pk[r] = hb;
        }
        st_sys8(hkT_b + (size_t)(h0 + l15)*CC + m0 + q*4, pk);
      } else {
#pragma unroll
        for (int r = 0; r < 4; ++r){
          int c = m0 + q*4 + r;
          float hqv = acc[r] + bb;
          float s2  = 1.f/(1.f+expf(-hqv));
          s_hq[c*16 + l15] = f2bf(hqv * s2);
        }
      }
    }
    __syncthreads();
    // coalesced burst stores: own hk tile + own hq tile (each contiguous 2 KB)
    if (tid < 128){
      st_sys16(hk_b + (size_t)tl*1024 + tid*8, *(const fragAB*)(s_hk + tid*8));
    } else if (tid < 256){
      int i = tid - 128;
      st_sys16(hq_b + (size_t)tl*1024 + i*8, *(const fragAB*)(s_hq + i*8));
    }
    ph++; bar_sync(slots, ph, tl);

    // ======== PHASE B ========
    {
      const u16* Ah = (wid < 4) ? hq_b : hk_b;
      int m0 = (wid & 3) * 16;
      fragC acc = zeroC();
      fragAB va[4], vb[4], hfr[8];
      float vv[4];
      if (wid >= 4){
#pragma unroll
        for (int r = 0; r < 4; ++r)
          vv[r] = V[((size_t)b*SS + (size_t)t*CC + m0 + q*4 + r)*DD + d0 + l15];
      }
#pragma unroll
      for (int j = 0; j < 4; ++j) ld_sys(va[j], taddr(Ah, m0 + l15, j*32 + qk));
#pragma unroll
      for (int j = 0; j < 4; ++j) ld_sys(vb[j], taddr(Ah, m0 + l15, 128 + j*32 + qk));
      WAITVM(4);
#pragma unroll
      for (int j = 0; j < 4; ++j) acc = MFMA16(va[j], frag_lds(s_w2, 520, 0, j*32, lane), acc);
#pragma unroll
      for (int j = 0; j < 4; ++j) ld_sys(va[j], taddr(Ah, m0 + l15, 256 + j*32 + qk));
      WAITVM(4);
#pragma unroll
      for (int j = 0; j < 4; ++j) acc = MFMA16(vb[j], frag_lds(s_w2, 520, 0, 128 + j*32, lane), acc);
#pragma unroll
      for (int j = 0; j < 4; ++j) ld_sys(vb[j], taddr(Ah, m0 + l15, 384 + j*32 + qk));
      WAITVM(4);
#pragma unroll
      for (int j = 0; j < 4; ++j) acc = MFMA16(va[j], frag_lds(s_w2, 520, 0, 256 + j*32, lane), acc);
#pragma unroll
      for (int nf = 0; nf < 4; ++nf)
#pragma unroll
        for (int kk = 0; kk < 2; ++kk)
          ld_sys(hfr[nf*2+kk], hkT_b + (size_t)(wid*64 + nf*16 + l15)*CC + kk*32 + qk);
      WAITVM(8);
#pragma unroll
      for (int j = 0; j < 4; ++j) acc = MFMA16(vb[j], frag_lds(s_w2, 520, 0, 384 + j*32, lane), acc);

      float bb = s_b2[l15];
      if (wid < 4){
#pragma unroll
        for (int r = 0; r < 4; ++r){
          int c = m0 + q*4 + r;
          __builtin_nontemporal_store(acc[r] + bb,
            &out[((size_t)b*SS + (size_t)t*CC + c)*DD + d0 + l15]);
        }
      } else {
#pragma unroll
        for (int r = 0; r < 4; ++r){
          int c = m0 + q*4 + r;
          float dvv = (acc[r] + bb - vv[r]) * (2.f/512.f);
          short db_ = f2bf(dvv);
          s_hk[c*16 + l15] = db_;       // dv staging (reuses s_hk)
          s_t[l15*72 + c]  = db_;       // dvT for g_w2 A-operand
        }
      }
      __syncthreads();
      // hfr guaranteed: wid<4 has 4 out-stores newest; wid>=4 has nothing after hfr
      if (wid < 4) { WAITVM(4); } else { WAITVM(0); }
      // dv burst store (contiguous own tile)
      if (tid < 128)
        st_sys16(dv_b + (size_t)tl*1024 + tid*8, *(const fragAB*)(s_hk + tid*8));
      // g_w2 [16 d][512 h], K = 64 c; updates; w2T stores; b2; s_pf prefetch
      {
        fragC ag[4];
#pragma unroll
        for (int i = 0; i < 4; ++i) ag[i] = zeroC();
#pragma unroll
        for (int kk = 0; kk < 2; ++kk){
          fragAB af = frag_lds(s_t, 72, 0, kk*32, lane);
#pragma unroll
          for (int nf = 0; nf < 4; ++nf)
            ag[nf] = MFMA16(af, hfr[nf*2+kk], ag[nf]);
        }
        // s_pf prefetch: issue loads early (hide RTT under update VALU)
        fragAB t0, t1;
        int hr = tid >> 5;
        int c0 = (tid & 31) << 4;
        if (t + 1 < NCH){
          const u16* w2Tp = w2Tb + (size_t)(t&1)*W2TBUF + (size_t)b*DD*LWW;
          const u16* src = w2Tp + (size_t)(h0 + hr)*DD + c0;
          ld_sys(t0, src);
          ld_sys(t1, src + 8);
        }
        const float* g3 = aet + ((size_t)b*NCH + t) * 3;
        float ga = g3[0], ge = g3[1], gth = g3[2];
        u16* w2Tn = w2Tb + (size_t)((t+1)&1)*W2TBUF + (size_t)b*DD*LWW;
#pragma unroll
        for (int nf = 0; nf < 4; ++nf){
          u16x4 pk;
#pragma unroll
          for (int r = 0; r < 4; ++r){
            float g  = ag[nf][r] * (1.f/64.f);
            float m_ = ge*mw2f[nf*4+r] - gth*g;
            float w_ = (1.f-ga)*w2f[nf*4+r] + m_;
            mw2f[nf*4+r] = m_; w2f[nf*4+r] = w_;
            short wb = f2bf(w_);
            s_w2[(q*4+r)*520 + wid*64 + nf*16 + l15] = wb;
            pk[r] = wb;
          }
          st_sys8(w2Tn + (size_t)(wid*64 + nf*16 + l15)*DD + d0 + q*4, pk);
        }
        if (tid < 16){
          const fragAB* row = (const fragAB*)(s_t + tid*72);
          float s = 0.f;
#pragma unroll
          for (int j = 0; j < 8; ++j){
            fragAB v = row[j];
#pragma unroll
            for (int i = 0; i < 8; ++i) s += bf2f(v[i]);
          }
          float gb = s * (1.f/64.f);
          float m_ = ge*s_mb2[tid] - gth*gb;
          float bn = (1.f-ga)*s_b2[tid] + m_;
          s_mb2[tid] = m_; s_b2[tid] = bn;
        }
        if (t + 1 < NCH){
          WAITVM(0);
          *(fragAB*)(s_pf + hr*520 + c0)     = t0;
          *(fragAB*)(s_pf + hr*520 + c0 + 8) = t1;
        }
      }
    }
    ph++; bar_sync(slots, ph, tl);
  }
}

extern "C" void kernel_launch(void* const* d_in, const int* in_sizes, int n_in,
                              void* d_out, int out_size, void* d_ws, size_t ws_size,
                              hipStream_t stream){
  const float* x   = (const float*)d_in[0];
  const float* Wq  = (const float*)d_in[1];
  const float* Wk  = (const float*)d_in[2];
  const float* Wv  = (const float*)d_in[3];
  const float* iw1 = (const float*)d_in[4];
  const float* ib1 = (const float*)d_in[5];
  const float* iw2 = (const float*)d_in[6];
  const float* ib2 = (const float*)d_in[7];
  const float* aw  = (const float*)d_in[8];
  const float* ab  = (const float*)d_in[9];
  const float* ew  = (const float*)d_in[10];
  const float* eb  = (const float*)d_in[11];
  const float* tw  = (const float*)d_in[12];
  const float* tb  = (const float*)d_in[13];
  float* out = (float*)d_out;

  float* fw = (float*)d_ws;
  float* V    = fw;  fw += (size_t)BB*SS*DD;
  float* aet  = fw;  fw += (size_t)BB*NCH*3 + 64;
  unsigned* bar = (unsigned*)fw; fw += 4096;
  u16* xb   = (u16*)fw;                       // aliased as KTg after k_proj
  u16* Wc   = xb   + (size_t)BB*SS*DD;
  u16* Qb   = Wc   + (size_t)3*DD*DD;
  u16* Kb   = Qb   + (size_t)BB*SS*DD;
  u16* hkb  = Kb   + (size_t)BB*SS*DD;
  u16* hqs  = hkb  + (size_t)BB*CC*LWW;
  u16* hkT  = hqs  + (size_t)BB*CC*LWW;
  u16* dvpb = hkT  + (size_t)BB*LWW*CC;
  u16* w2Tb = dvpb + (size_t)BB*CC*DD;        // 2 buffers of BB*DD*LWW
  u16* KTg  = xb;

  k_cvt  <<<8960, 256, 0, stream>>>(x, Wq, Wk, Wv, xb, Wc, bar);
  k_proj <<<3072, 256, 0, stream>>>(xb, Wc, Qb, Kb, V);
  k_norm <<<8192, 256, 0, stream>>>(Qb, Kb);
  k_trans<<<2048, 256, 0, stream>>>(Kb, KTg);
  k_gates<<<256,  256, 0, stream>>>(x, aw, ab, ew, eb, tw, tb, aet);
  k_scan <<<128,  512, 0, stream>>>(Qb, Kb, KTg, V, aet, iw1, ib1, iw2, ib2,
                                    hkb, hqs, hkT, dvpb, w2Tb, out, bar);
}